// Round 1
// baseline (897.180 us; speedup 1.0000x reference)
//
#include <hip/hip_runtime.h>
#include <cmath>

typedef unsigned short u16;
typedef __attribute__((ext_vector_type(4))) float f32x4;
typedef __attribute__((ext_vector_type(4))) unsigned int u32x4;
typedef __attribute__((ext_vector_type(8))) __bf16 bf16x8;

__device__ __forceinline__ u16 f2b(float f) {
  unsigned int u = __builtin_bit_cast(unsigned int, f);
  return (u16)((u + 0x7fffu + ((u >> 16) & 1u)) >> 16);  // RNE
}
__device__ __forceinline__ float b2f(u16 h) {
  unsigned int u = ((unsigned int)h) << 16;
  return __builtin_bit_cast(float, u);
}

// ---------------------------------------------------------------------------
// Generic bf16-MFMA GEMM, 128x128 tile, BK=32, 256 threads (4 waves, 2x2).
// Logical A is MxK: A(m,k) = TA ? Aload[k*lda+m] : Aload[m*lda+k]
// Logical B is KxN: B(k,n) = TB ? Bload[n*ldb+k] : Bload[k*ldb+n]
// AF/BF: 0 = f32 source (converted to bf16 during staging), 1 = bf16 source.
// EPI: 0 = store bf16 C + bias[n]
//      1 = TGSA reduce: v = sigmoid(acc+bias[n]) * tok[m,n]; colsum/bsum/bsumsq
//      2 = store bf16 (acc*scale)  (raw attention scores)
//      3 = reduce-only: colsum[b,n], bsum[b], bsumsq[b]   (b = blockIdx.z)
// All dims must be multiples of 128 (M,N) and 32 (K) -- true for this problem.
// ---------------------------------------------------------------------------
template <int AF, int BF, int TA, int TB, int EPI>
__global__ __launch_bounds__(256) void gemm_k(
    const void* __restrict__ Ap, const void* __restrict__ Bp,
    u16* __restrict__ Cp, const float* __restrict__ bias,
    const float* __restrict__ tokp, float* __restrict__ colsum,
    float* __restrict__ bstat, int M, int N, int K, int lda, int ldb, int ldc,
    long sA, long sB, long sC, float scale) {
  __shared__ u16 Al[128][40];  // +8 pad: 80B row stride, 16B aligned
  __shared__ u16 Bl[128][40];  // Bl[n][k]
  const int tid = threadIdx.x;
  const int z = blockIdx.z;
  const int tileM = blockIdx.y << 7, tileN = blockIdx.x << 7;

  const char* Abase = (const char*)Ap + (size_t)z * (size_t)sA * (AF ? 2 : 4);
  const char* Bbase = (const char*)Bp + (size_t)z * (size_t)sB * (BF ? 2 : 4);

  f32x4 acc[4][4];
#pragma unroll
  for (int i = 0; i < 4; ++i)
#pragma unroll
    for (int j = 0; j < 4; ++j) acc[i][j] = (f32x4){0.f, 0.f, 0.f, 0.f};

  const int lane = tid & 63, wid = tid >> 6;
  const int wr = (wid >> 1) << 6, wc = (wid & 1) << 6;
  const int fr = lane & 15, fg = lane >> 4;

  for (int k0 = 0; k0 < K; k0 += 32) {
    // ---- stage A -> Al[m][k] ----
    if constexpr (TA == 0) {
      const int row = tid >> 1, half = tid & 1;
      u16* dst = &Al[row][half << 4];
      if constexpr (AF == 0) {
        const float* s =
            (const float*)Abase + (size_t)(tileM + row) * lda + k0 + (half << 4);
        union { u16 u[16]; u32x4 q[2]; } pk;
#pragma unroll
        for (int i = 0; i < 4; ++i) {
          f32x4 v = ((const f32x4*)s)[i];
#pragma unroll
          for (int j = 0; j < 4; ++j) pk.u[i * 4 + j] = f2b(v[j]);
        }
        ((u32x4*)dst)[0] = pk.q[0];
        ((u32x4*)dst)[1] = pk.q[1];
      } else {
        const u16* s =
            (const u16*)Abase + (size_t)(tileM + row) * lda + k0 + (half << 4);
        ((u32x4*)dst)[0] = ((const u32x4*)s)[0];
        ((u32x4*)dst)[1] = ((const u32x4*)s)[1];
      }
    } else {  // A(m,k) = Aload[k*lda+m] : transpose-stage
      const int k = tid >> 3, m0 = (tid & 7) << 4;
      if constexpr (AF == 0) {
        const float* s = (const float*)Abase + (size_t)(k0 + k) * lda + tileM + m0;
#pragma unroll
        for (int i = 0; i < 16; ++i) Al[m0 + i][k] = f2b(s[i]);
      } else {
        const u16* s = (const u16*)Abase + (size_t)(k0 + k) * lda + tileM + m0;
#pragma unroll
        for (int i = 0; i < 16; ++i) Al[m0 + i][k] = s[i];
      }
    }
    // ---- stage B -> Bl[n][k] ----
    if constexpr (TB == 1) {  // B(k,n) = Bload[n*ldb+k] : direct rows
      const int n = tid >> 1, half = tid & 1;
      u16* dst = &Bl[n][half << 4];
      if constexpr (BF == 0) {
        const float* s =
            (const float*)Bbase + (size_t)(tileN + n) * ldb + k0 + (half << 4);
        union { u16 u[16]; u32x4 q[2]; } pk;
#pragma unroll
        for (int i = 0; i < 4; ++i) {
          f32x4 v = ((const f32x4*)s)[i];
#pragma unroll
          for (int j = 0; j < 4; ++j) pk.u[i * 4 + j] = f2b(v[j]);
        }
        ((u32x4*)dst)[0] = pk.q[0];
        ((u32x4*)dst)[1] = pk.q[1];
      } else {
        const u16* s =
            (const u16*)Bbase + (size_t)(tileN + n) * ldb + k0 + (half << 4);
        ((u32x4*)dst)[0] = ((const u32x4*)s)[0];
        ((u32x4*)dst)[1] = ((const u32x4*)s)[1];
      }
    } else {  // B(k,n) = Bload[k*ldb+n] : transpose-stage
      const int k = tid >> 3, n0 = (tid & 7) << 4;
      if constexpr (BF == 0) {
        const float* s = (const float*)Bbase + (size_t)(k0 + k) * ldb + tileN + n0;
#pragma unroll
        for (int i = 0; i < 16; ++i) Bl[n0 + i][k] = f2b(s[i]);
      } else {
        const u16* s = (const u16*)Bbase + (size_t)(k0 + k) * ldb + tileN + n0;
#pragma unroll
        for (int i = 0; i < 16; ++i) Bl[n0 + i][k] = s[i];
      }
    }
    __syncthreads();
    // ---- compute: 16 MFMAs ----
    bf16x8 av[4], bvv[4];
#pragma unroll
    for (int m = 0; m < 4; ++m)
      av[m] = *(const bf16x8*)&Al[wr + (m << 4) + fr][fg << 3];
#pragma unroll
    for (int n = 0; n < 4; ++n)
      bvv[n] = *(const bf16x8*)&Bl[wc + (n << 4) + fr][fg << 3];
#pragma unroll
    for (int m = 0; m < 4; ++m)
#pragma unroll
      for (int n = 0; n < 4; ++n)
        acc[m][n] =
            __builtin_amdgcn_mfma_f32_16x16x32_bf16(av[m], bvv[n], acc[m][n], 0, 0, 0);
    __syncthreads();
  }

  // ---- epilogue ----
  if constexpr (EPI == 0 || EPI == 2) {
#pragma unroll
    for (int m = 0; m < 4; ++m) {
#pragma unroll
      for (int n = 0; n < 4; ++n) {
        const int gcol = tileN + wc + (n << 4) + fr;
#pragma unroll
        for (int r = 0; r < 4; ++r) {
          const int grow = tileM + wr + (m << 4) + (fg << 2) + r;
          float v = acc[m][n][r];
          if constexpr (EPI == 0) v += bias[gcol];
          else v *= scale;
          Cp[(size_t)z * sC + (size_t)grow * ldc + gcol] = f2b(v);
        }
      }
    }
  } else {
    __shared__ float scol[128];
    __shared__ float sred[2];
    if (tid < 128) scol[tid] = 0.f;
    if (tid == 0) { sred[0] = 0.f; sred[1] = 0.f; }
    __syncthreads();
    float ls = 0.f, lq = 0.f;
#pragma unroll
    for (int n = 0; n < 4; ++n) {
      float cpart = 0.f;
      const int gcol = tileN + wc + (n << 4) + fr;
#pragma unroll
      for (int m = 0; m < 4; ++m) {
#pragma unroll
        for (int r = 0; r < 4; ++r) {
          float v = acc[m][n][r];
          if constexpr (EPI == 1) {
            const int grow = tileM + wr + (m << 4) + (fg << 2) + r;
            float pre = v + bias[gcol];
            float g = 1.f / (1.f + __expf(-pre));
            v = g * tokp[(size_t)grow * 768 + gcol];
          }
          cpart += v; ls += v; lq += v * v;
        }
      }
      atomicAdd(&scol[wc + (n << 4) + fr], cpart);
    }
    atomicAdd(&sred[0], ls);
    atomicAdd(&sred[1], lq);
    __syncthreads();
    const int b = (EPI == 1) ? (tileM >> 9) : z;
    if (tid < 128) atomicAdd(&colsum[(size_t)b * 768 + tileN + tid], scol[tid]);
    if (tid == 0) {
      atomicAdd(&bstat[b], sred[0]);
      atomicAdd(&bstat[32 + b], sred[1]);
    }
  }
}

// in-place row softmax on bf16 scores; block=256, grid=numRows
template <int LEN>
__global__ __launch_bounds__(256) void softmax_k(u16* __restrict__ data) {
  constexpr int NP = LEN / 256;
  const int row = blockIdx.x, tid = threadIdx.x;
  u16* p = data + (size_t)row * LEN;
  const int lane = tid & 63, wid = tid >> 6;
  float v[NP];
  float mx = -1e30f;
#pragma unroll
  for (int i = 0; i < NP; ++i) { v[i] = b2f(p[tid + (i << 8)]); mx = fmaxf(mx, v[i]); }
#pragma unroll
  for (int o = 32; o > 0; o >>= 1) mx = fmaxf(mx, __shfl_xor(mx, o));
  __shared__ float red[4], red2[4];
  if (lane == 0) red[wid] = mx;
  __syncthreads();
  mx = fmaxf(fmaxf(red[0], red[1]), fmaxf(red[2], red[3]));
  float sum = 0.f;
#pragma unroll
  for (int i = 0; i < NP; ++i) { v[i] = __expf(v[i] - mx); sum += v[i]; }
#pragma unroll
  for (int o = 32; o > 0; o >>= 1) sum += __shfl_xor(sum, o);
  if (lane == 0) red2[wid] = sum;
  __syncthreads();
  sum = red2[0] + red2[1] + red2[2] + red2[3];
  const float inv = 1.f / sum;
#pragma unroll
  for (int i = 0; i < NP; ++i) p[tid + (i << 8)] = f2b(v[i] * inv);
}

// per-row: gate_t = relu(tok . W_ts + b_ts), rowsum, rowsumsq. 1 wave/row.
__global__ __launch_bounds__(256) void row_stats_k(
    const float* __restrict__ tok, const float* __restrict__ Wts,
    const float* __restrict__ bts, float* __restrict__ gate_t,
    float* __restrict__ rowsum, float* __restrict__ rowsumsq) {
  const int wid = threadIdx.x >> 6, lane = threadIdx.x & 63;
  const int row = blockIdx.x * 4 + wid;
  const float* p = tok + (size_t)row * 768;
  float s = 0.f, q = 0.f, g = 0.f;
#pragma unroll
  for (int i = 0; i < 12; ++i) {
    float t = p[lane + i * 64];
    s += t; q += t * t; g += t * Wts[lane + i * 64];
  }
#pragma unroll
  for (int o = 32; o > 0; o >>= 1) {
    s += __shfl_xor(s, o); q += __shfl_xor(q, o); g += __shfl_xor(g, o);
  }
  if (lane == 0) {
    gate_t[row] = fmaxf(g + bts[0], 0.f);
    rowsum[row] = s;
    rowsumsq[row] = q;
  }
}

// per-column: gate_f, colsum_tok, colsumsq_tok, colsum_tsgsa. grid (B,3)x256.
__global__ __launch_bounds__(256) void col_stats_k(
    const float* __restrict__ tok, const float* __restrict__ Wfs,
    const float* __restrict__ bfs, const float* __restrict__ gate_t,
    float* __restrict__ gate_f, float* __restrict__ colsum_tok,
    float* __restrict__ colsumsq_tok, float* __restrict__ colsum_tsg) {
  const int b = blockIdx.x, h = blockIdx.y * 256 + threadIdx.x;
  const float* p = tok + (size_t)b * 512 * 768 + h;
  const float* gt = gate_t + b * 512;
  float cs = 0.f, cq = 0.f, gf = 0.f, tg = 0.f;
#pragma unroll 4
  for (int s = 0; s < 512; ++s) {
    float t = p[(size_t)s * 768];
    cs += t; cq += t * t; gf += t * Wfs[s]; tg += t * gt[s];
  }
  const int idx = b * 768 + h;
  gate_f[idx] = fmaxf(gf + bfs[0], 0.f);
  colsum_tok[idx] = cs;
  colsumsq_tok[idx] = cq;
  colsum_tsg[idx] = tg;
}

// per-batch scalar stats for TSGSA and FSGSA. st: [tsg_s|tsg_q|fsg_s|fsg_q]x32
__global__ __launch_bounds__(256) void batch_stats_k(
    const float* __restrict__ gate_t, const float* __restrict__ rowsum,
    const float* __restrict__ rowsumsq, const float* __restrict__ gate_f,
    const float* __restrict__ colsum_tok, const float* __restrict__ colsumsq_tok,
    float* __restrict__ st) {
  __shared__ float red[4][256];
  const int b = blockIdx.x, tid = threadIdx.x;
  float ts = 0.f, tq = 0.f, fs = 0.f, fq = 0.f;
  for (int s = tid; s < 512; s += 256) {
    float g = gate_t[b * 512 + s];
    ts += g * rowsum[b * 512 + s];
    tq += g * g * rowsumsq[b * 512 + s];
  }
  for (int h = tid; h < 768; h += 256) {
    float g = gate_f[b * 768 + h];
    fs += g * colsum_tok[b * 768 + h];
    fq += g * g * colsumsq_tok[b * 768 + h];
  }
  red[0][tid] = ts; red[1][tid] = tq; red[2][tid] = fs; red[3][tid] = fq;
  __syncthreads();
  for (int o = 128; o > 0; o >>= 1) {
    if (tid < o) {
      red[0][tid] += red[0][tid + o];
      red[1][tid] += red[1][tid + o];
      red[2][tid] += red[2][tid + o];
      red[3][tid] += red[3][tid + o];
    }
    __syncthreads();
  }
  if (tid == 0) {
    st[b] = red[0][0]; st[32 + b] = red[1][0];
    st[64 + b] = red[2][0]; st[96 + b] = red[3][0];
  }
}

// build pooled [B, 7*768] from column sums + batch stats
__global__ __launch_bounds__(768) void pooled_k(
    const float* __restrict__ colsum_tok, const float* __restrict__ colsum_tsa,
    const float* __restrict__ bstat_tsa, const float* __restrict__ colsum_fsa,
    const float* __restrict__ bstat_fsa, const float* __restrict__ colsum_tgsa,
    const float* __restrict__ bstat_tgsa, const float* __restrict__ colsum_tsg,
    const float* __restrict__ gate_f, const float* __restrict__ st,
    float* __restrict__ pooled) {
  const int b = blockIdx.x, h = threadIdx.x;
  const float invS = 1.f / 512.f, invN = 1.f / (512.f * 768.f);
  const int i = b * 768 + h;
  float* pr = pooled + (size_t)b * 5376;
  pr[h] = colsum_tok[i] * invS;
  auto lnslot = [&](int slot, float cs, float bs, float bq) {
    float m = bs * invN;
    float var = bq * invN - m * m;
    pr[slot * 768 + h] = (cs * invS - m) * rsqrtf(var + 1e-8f);
  };
  lnslot(1, colsum_tsa[i], bstat_tsa[b], bstat_tsa[32 + b]);
  lnslot(2, colsum_fsa[i], bstat_fsa[b], bstat_fsa[32 + b]);
  lnslot(3, colsum_tgsa[i], bstat_tgsa[b], bstat_tgsa[32 + b]);
  const float fsg_cs = gate_f[i] * colsum_tok[i];
  lnslot(4, fsg_cs, st[64 + b], st[96 + b]);
  lnslot(5, colsum_tsg[i], st[b], st[32 + b]);
  lnslot(6, fsg_cs, st[64 + b], st[96 + b]);
}

// tmp1[b,k] = pooled[b,:] . W1[:,k] + b1[k].  grid (B,3)x256
__global__ __launch_bounds__(256) void fnn1_k(const float* __restrict__ pooled,
                                              const float* __restrict__ W1,
                                              const float* __restrict__ b1,
                                              float* __restrict__ tmp1) {
  __shared__ float sp[5376];
  const int b = blockIdx.x, k = blockIdx.y * 256 + threadIdx.x;
  for (int j = threadIdx.x; j < 5376; j += 256) sp[j] = pooled[(size_t)b * 5376 + j];
  __syncthreads();
  float a = b1[k];
#pragma unroll 8
  for (int j = 0; j < 5376; ++j) a += sp[j] * W1[(size_t)j * 768 + k];
  tmp1[b * 768 + k] = a;
}

// out[b,c] = tmp1[b,:] . W2[:,c] + b2[c]
__global__ void fnn2_k(const float* __restrict__ tmp1, const float* __restrict__ W2,
                       const float* __restrict__ b2, float* __restrict__ out) {
  const int t = threadIdx.x;
  if (t >= 96) return;
  const int b = t / 3, c = t % 3;
  float a = b2[c];
  for (int k = 0; k < 768; ++k) a += tmp1[b * 768 + k] * W2[k * 3 + c];
  out[b * 3 + c] = a;
}

extern "C" void kernel_launch(void* const* d_in, const int* in_sizes, int n_in,
                              void* d_out, int out_size, void* d_ws, size_t ws_size,
                              hipStream_t stream) {
  const float* tokens = (const float*)d_in[0];
  const float* Wq = (const float*)d_in[1];
  const float* bq = (const float*)d_in[2];
  const float* Wk = (const float*)d_in[3];
  const float* bk = (const float*)d_in[4];
  const float* Wv = (const float*)d_in[5];
  const float* bv = (const float*)d_in[6];
  const float* Wts = (const float*)d_in[7];
  const float* bts = (const float*)d_in[8];
  const float* Wfs = (const float*)d_in[9];
  const float* bfs = (const float*)d_in[10];
  const float* Wtg = (const float*)d_in[11];
  const float* btg = (const float*)d_in[12];
  const float* W1 = (const float*)d_in[13];
  const float* b1 = (const float*)d_in[14];
  const float* W2 = (const float*)d_in[15];
  const float* b2 = (const float*)d_in[16];
  float* out = (float*)d_out;

  char* ws = (char*)d_ws;
  size_t off = 0;
  auto take = [&](size_t bytes) -> char* {
    char* p = ws + off;
    off += (bytes + 255) & ~(size_t)255;
    return p;
  };
  u16* Qb = (u16*)take((size_t)16384 * 768 * 2);
  u16* Kb = (u16*)take((size_t)16384 * 768 * 2);
  u16* Vb = (u16*)take((size_t)16384 * 768 * 2);
  u16* attb = (u16*)take((size_t)32 * 512 * 512 * 2);
  u16* attNb = (u16*)take((size_t)32 * 768 * 768 * 2);
  // --- zeroed (atomic-accumulated) region: keep contiguous ---
  char* zbase = ws + off;
  float* colsum_tsa = (float*)take(24576 * 4);
  float* colsum_fsa = (float*)take(24576 * 4);
  float* colsum_tgsa = (float*)take(24576 * 4);
  float* bstat_tsa = (float*)take(64 * 4);
  float* bstat_fsa = (float*)take(64 * 4);
  float* bstat_tgsa = (float*)take(64 * 4);
  size_t zbytes = (size_t)((ws + off) - zbase);
  // --- fully-overwritten buffers ---
  float* colsum_tsg = (float*)take(24576 * 4);
  float* gate_t = (float*)take(16384 * 4);
  float* rowsum = (float*)take(16384 * 4);
  float* rowsumsq = (float*)take(16384 * 4);
  float* gate_f = (float*)take(24576 * 4);
  float* colsum_tok = (float*)take(24576 * 4);
  float* colsumsq_tok = (float*)take(24576 * 4);
  float* st4 = (float*)take(128 * 4);
  float* pooled = (float*)take((size_t)32 * 5376 * 4);
  float* tmp1 = (float*)take((size_t)32 * 768 * 4);

  hipMemsetAsync(zbase, 0, zbytes, stream);

  const float scale = 1.0f / sqrtf(768.0f);
  const dim3 blk(256);

  // projections: Q, K, V (store bf16), TGSA (gated reduce)
  gemm_k<0, 0, 0, 0, 0><<<dim3(6, 128, 1), blk, 0, stream>>>(
      tokens, Wq, Qb, bq, nullptr, nullptr, nullptr, 16384, 768, 768, 768, 768,
      768, 0, 0, 0, 0.f);
  gemm_k<0, 0, 0, 0, 0><<<dim3(6, 128, 1), blk, 0, stream>>>(
      tokens, Wk, Kb, bk, nullptr, nullptr, nullptr, 16384, 768, 768, 768, 768,
      768, 0, 0, 0, 0.f);
  gemm_k<0, 0, 0, 0, 0><<<dim3(6, 128, 1), blk, 0, stream>>>(
      tokens, Wv, Vb, bv, nullptr, nullptr, nullptr, 16384, 768, 768, 768, 768,
      768, 0, 0, 0, 0.f);
  gemm_k<0, 0, 0, 0, 1><<<dim3(6, 128, 1), blk, 0, stream>>>(
      tokens, Wtg, nullptr, btg, tokens, colsum_tgsa, bstat_tgsa, 16384, 768,
      768, 768, 768, 768, 0, 0, 0, 0.f);

  // token attention scores: att[s,t] = Q[s,:].K[t,:] * scale   (NT)
  gemm_k<1, 1, 0, 1, 2><<<dim3(4, 4, 32), blk, 0, stream>>>(
      Qb, Kb, attb, nullptr, nullptr, nullptr, nullptr, 512, 512, 768, 768, 768,
      512, 393216, 393216, 262144, scale);
  softmax_k<512><<<16384, 256, 0, stream>>>(attb);

  // feature attention scores: attN[h,g] = sum_s Q[s,h]K[s,g] * scale  (TN)
  gemm_k<1, 1, 1, 0, 2><<<dim3(6, 6, 32), blk, 0, stream>>>(
      Qb, Kb, attNb, nullptr, nullptr, nullptr, nullptr, 768, 768, 512, 768,
      768, 768, 393216, 393216, 589824, scale);
  softmax_k<768><<<24576, 256, 0, stream>>>(attNb);

  // TSA = att @ V  -> reduce only
  gemm_k<1, 1, 0, 0, 3><<<dim3(6, 4, 32), blk, 0, stream>>>(
      attb, Vb, nullptr, nullptr, nullptr, colsum_tsa, bstat_tsa, 512, 768, 512,
      512, 768, 0, 262144, 393216, 0, 0.f);
  // FSA = V @ attN -> reduce only
  gemm_k<1, 1, 0, 0, 3><<<dim3(6, 4, 32), blk, 0, stream>>>(
      Vb, attNb, nullptr, nullptr, nullptr, colsum_fsa, bstat_fsa, 512, 768,
      768, 768, 768, 0, 393216, 589824, 0, 0.f);

  // gate-branch statistics
  row_stats_k<<<4096, blk, 0, stream>>>(tokens, Wts, bts, gate_t, rowsum, rowsumsq);
  col_stats_k<<<dim3(32, 3), blk, 0, stream>>>(tokens, Wfs, bfs, gate_t, gate_f,
                                               colsum_tok, colsumsq_tok, colsum_tsg);
  batch_stats_k<<<32, blk, 0, stream>>>(gate_t, rowsum, rowsumsq, gate_f,
                                        colsum_tok, colsumsq_tok, st4);

  pooled_k<<<32, 768, 0, stream>>>(colsum_tok, colsum_tsa, bstat_tsa, colsum_fsa,
                                   bstat_fsa, colsum_tgsa, bstat_tgsa, colsum_tsg,
                                   gate_f, st4, pooled);
  fnn1_k<<<dim3(32, 3), blk, 0, stream>>>(pooled, W1, b1, tmp1);
  fnn2_k<<<1, 128, 0, stream>>>(tmp1, W2, b2, out);
}

// Round 2
// 583.979 us; speedup vs baseline: 1.5363x; 1.5363x over previous
//
#include <hip/hip_runtime.h>
#include <cmath>

typedef unsigned short u16;
typedef __attribute__((ext_vector_type(4))) float f32x4;
typedef __attribute__((ext_vector_type(4))) unsigned int u32x4;
typedef __attribute__((ext_vector_type(8))) __bf16 bf16x8;

__device__ __forceinline__ u16 f2b(float f) {
  unsigned int u = __builtin_bit_cast(unsigned int, f);
  return (u16)((u + 0x7fffu + ((u >> 16) & 1u)) >> 16);  // RNE
}
__device__ __forceinline__ float b2f(u16 h) {
  unsigned int u = ((unsigned int)h) << 16;
  return __builtin_bit_cast(float, u);
}

// ---------------------------------------------------------------------------
// Generic bf16-MFMA GEMM, 128x128 tile, BK=32, 256 threads (4 waves, 2x2).
// Logical A is MxK: A(m,k) = TA ? Aload[k*lda+m] : Aload[m*lda+k]
// Logical B is KxN: B(k,n) = TB ? Bload[n*ldb+k] : Bload[k*ldb+n]
// AF/BF: 0 = f32 source (converted during staging), 1 = bf16 source.
// EPI: 0 = store bf16 C + bias[n]; if CpT, also store C^T packed (ldct=16384)
//      1 = TGSA reduce: v = sigmoid(acc+bias[n]) * tok[m,n]; colsum/bsum/bsumsq
//      2 = store bf16 (acc*scale)  (raw attention scores)
//      3 = reduce-only: colsum[b,n], bsum[b], bsumsq[b]   (b = blockIdx.z)
// ---------------------------------------------------------------------------
template <int AF, int BF, int TA, int TB, int EPI>
__global__ __launch_bounds__(256) void gemm_k(
    const void* __restrict__ Ap, const void* __restrict__ Bp,
    u16* __restrict__ Cp, u16* __restrict__ CpT, const float* __restrict__ bias,
    const float* __restrict__ tokp, float* __restrict__ colsum,
    float* __restrict__ bstat, int M, int N, int K, int lda, int ldb, int ldc,
    long sA, long sB, long sC, float scale) {
  __shared__ u16 Al[128][40];  // +8 pad: 80B row stride, 16B aligned
  __shared__ u16 Bl[128][40];  // Bl[n][k]
  const int tid = threadIdx.x;
  const int z = blockIdx.z;
  const int tileM = blockIdx.y << 7, tileN = blockIdx.x << 7;

  const char* Abase = (const char*)Ap + (size_t)z * (size_t)sA * (AF ? 2 : 4);
  const char* Bbase = (const char*)Bp + (size_t)z * (size_t)sB * (BF ? 2 : 4);

  f32x4 acc[4][4];
#pragma unroll
  for (int i = 0; i < 4; ++i)
#pragma unroll
    for (int j = 0; j < 4; ++j) acc[i][j] = (f32x4){0.f, 0.f, 0.f, 0.f};

  const int lane = tid & 63, wid = tid >> 6;
  const int wr = (wid >> 1) << 6, wc = (wid & 1) << 6;
  const int fr = lane & 15, fg = lane >> 4;

  for (int k0 = 0; k0 < K; k0 += 32) {
    // ---- stage A -> Al[m][k] ----
    if constexpr (TA == 0) {
      const int row = tid >> 1, half = tid & 1;
      u16* dst = &Al[row][half << 4];
      if constexpr (AF == 0) {
        const float* s =
            (const float*)Abase + (size_t)(tileM + row) * lda + k0 + (half << 4);
        union { u16 u[16]; u32x4 q[2]; } pk;
#pragma unroll
        for (int i = 0; i < 4; ++i) {
          f32x4 v = ((const f32x4*)s)[i];
#pragma unroll
          for (int j = 0; j < 4; ++j) pk.u[i * 4 + j] = f2b(v[j]);
        }
        ((u32x4*)dst)[0] = pk.q[0];
        ((u32x4*)dst)[1] = pk.q[1];
      } else {
        const u16* s =
            (const u16*)Abase + (size_t)(tileM + row) * lda + k0 + (half << 4);
        ((u32x4*)dst)[0] = ((const u32x4*)s)[0];
        ((u32x4*)dst)[1] = ((const u32x4*)s)[1];
      }
    } else {  // transpose-stage (scalar)
      const int k = tid >> 3, m0 = (tid & 7) << 4;
      if constexpr (AF == 0) {
        const float* s = (const float*)Abase + (size_t)(k0 + k) * lda + tileM + m0;
#pragma unroll
        for (int i = 0; i < 16; ++i) Al[m0 + i][k] = f2b(s[i]);
      } else {
        const u16* s = (const u16*)Abase + (size_t)(k0 + k) * lda + tileM + m0;
#pragma unroll
        for (int i = 0; i < 16; ++i) Al[m0 + i][k] = s[i];
      }
    }
    // ---- stage B -> Bl[n][k] ----
    if constexpr (TB == 1) {  // direct rows
      const int n = tid >> 1, half = tid & 1;
      u16* dst = &Bl[n][half << 4];
      if constexpr (BF == 0) {
        const float* s =
            (const float*)Bbase + (size_t)(tileN + n) * ldb + k0 + (half << 4);
        union { u16 u[16]; u32x4 q[2]; } pk;
#pragma unroll
        for (int i = 0; i < 4; ++i) {
          f32x4 v = ((const f32x4*)s)[i];
#pragma unroll
          for (int j = 0; j < 4; ++j) pk.u[i * 4 + j] = f2b(v[j]);
        }
        ((u32x4*)dst)[0] = pk.q[0];
        ((u32x4*)dst)[1] = pk.q[1];
      } else {
        const u16* s =
            (const u16*)Bbase + (size_t)(tileN + n) * ldb + k0 + (half << 4);
        ((u32x4*)dst)[0] = ((const u32x4*)s)[0];
        ((u32x4*)dst)[1] = ((const u32x4*)s)[1];
      }
    } else {  // transpose-stage (scalar)
      const int k = tid >> 3, n0 = (tid & 7) << 4;
      if constexpr (BF == 0) {
        const float* s = (const float*)Bbase + (size_t)(k0 + k) * ldb + tileN + n0;
#pragma unroll
        for (int i = 0; i < 16; ++i) Bl[n0 + i][k] = f2b(s[i]);
      } else {
        const u16* s = (const u16*)Bbase + (size_t)(k0 + k) * ldb + tileN + n0;
#pragma unroll
        for (int i = 0; i < 16; ++i) Bl[n0 + i][k] = s[i];
      }
    }
    __syncthreads();
    // ---- compute: 16 MFMAs ----
    bf16x8 av[4], bvv[4];
#pragma unroll
    for (int m = 0; m < 4; ++m)
      av[m] = *(const bf16x8*)&Al[wr + (m << 4) + fr][fg << 3];
#pragma unroll
    for (int n = 0; n < 4; ++n)
      bvv[n] = *(const bf16x8*)&Bl[wc + (n << 4) + fr][fg << 3];
#pragma unroll
    for (int m = 0; m < 4; ++m)
#pragma unroll
      for (int n = 0; n < 4; ++n)
        acc[m][n] =
            __builtin_amdgcn_mfma_f32_16x16x32_bf16(av[m], bvv[n], acc[m][n], 0, 0, 0);
    __syncthreads();
  }

  // ---- epilogue ----
  if constexpr (EPI == 0 || EPI == 2) {
#pragma unroll
    for (int m = 0; m < 4; ++m) {
#pragma unroll
      for (int n = 0; n < 4; ++n) {
        const int gcol = tileN + wc + (n << 4) + fr;
#pragma unroll
        for (int r = 0; r < 4; ++r) {
          const int grow = tileM + wr + (m << 4) + (fg << 2) + r;
          float v = acc[m][n][r];
          if constexpr (EPI == 0) v += bias[gcol];
          else v *= scale;
          Cp[(size_t)z * sC + (size_t)grow * ldc + gcol] = f2b(v);
        }
      }
    }
    if constexpr (EPI == 0) {
      if (CpT) {  // transposed store: CpT[gcol][grow], packed 4x u16
#pragma unroll
        for (int m = 0; m < 4; ++m) {
#pragma unroll
          for (int n = 0; n < 4; ++n) {
            const int gcol = tileN + wc + (n << 4) + fr;
            const int grow0 = tileM + wr + (m << 4) + (fg << 2);
            union { u16 u[4]; unsigned long long q; } pk;
#pragma unroll
            for (int r = 0; r < 4; ++r) pk.u[r] = f2b(acc[m][n][r] + bias[gcol]);
            *(unsigned long long*)&CpT[(size_t)gcol * 16384 + grow0] = pk.q;
          }
        }
      }
    }
  } else {
    __shared__ float scol[128];
    __shared__ float sred[2];
    if (tid < 128) scol[tid] = 0.f;
    if (tid == 0) { sred[0] = 0.f; sred[1] = 0.f; }
    __syncthreads();
    float ls = 0.f, lq = 0.f;
#pragma unroll
    for (int n = 0; n < 4; ++n) {
      float cpart = 0.f;
      const int gcol = tileN + wc + (n << 4) + fr;
#pragma unroll
      for (int m = 0; m < 4; ++m) {
#pragma unroll
        for (int r = 0; r < 4; ++r) {
          float v = acc[m][n][r];
          if constexpr (EPI == 1) {
            const int grow = tileM + wr + (m << 4) + (fg << 2) + r;
            float pre = v + bias[gcol];
            float g = 1.f / (1.f + __expf(-pre));
            v = g * tokp[(size_t)grow * 768 + gcol];
          }
          cpart += v; ls += v; lq += v * v;
        }
      }
      atomicAdd(&scol[wc + (n << 4) + fr], cpart);
    }
    atomicAdd(&sred[0], ls);
    atomicAdd(&sred[1], lq);
    __syncthreads();
    const int b = (EPI == 1) ? (tileM >> 9) : z;
    if (tid < 128) atomicAdd(&colsum[(size_t)b * 768 + tileN + tid], scol[tid]);
    if (tid == 0) {
      atomicAdd(&bstat[b], sred[0]);
      atomicAdd(&bstat[32 + b], sred[1]);
    }
  }
}

// tokens f32 -> bf16, 8 elems/thread
__global__ __launch_bounds__(256) void cvt_tok_k(const float* __restrict__ in,
                                                 u16* __restrict__ out) {
  const size_t i = ((size_t)blockIdx.x * 256 + threadIdx.x) * 8;
  f32x4 a = *(const f32x4*)(in + i), b = *(const f32x4*)(in + i + 4);
  union { u16 u[8]; u32x4 q; } pk;
#pragma unroll
  for (int j = 0; j < 4; ++j) { pk.u[j] = f2b(a[j]); pk.u[4 + j] = f2b(b[j]); }
  *(u32x4*)(out + i) = pk.q;
}

// W [768][768] f32 -> WT [768][768] bf16 (transposed)
__global__ __launch_bounds__(256) void transpose_w_k(const float* __restrict__ W,
                                                     u16* __restrict__ WT) {
  __shared__ float t[64][65];
  const int r0 = blockIdx.y << 6, c0 = blockIdx.x << 6;
  for (int i = threadIdx.x; i < 4096; i += 256) {
    int r = i >> 6, c = i & 63;
    t[r][c] = W[(size_t)(r0 + r) * 768 + c0 + c];
  }
  __syncthreads();
  for (int i = threadIdx.x; i < 4096; i += 256) {
    int rr = i >> 6, cc = i & 63;
    WT[(size_t)(c0 + rr) * 768 + r0 + cc] = f2b(t[cc][rr]);
  }
}

// in-place row softmax on bf16 scores; block=256, grid=numRows
template <int LEN>
__global__ __launch_bounds__(256) void softmax_k(u16* __restrict__ data) {
  constexpr int NP = LEN / 256;
  const int row = blockIdx.x, tid = threadIdx.x;
  u16* p = data + (size_t)row * LEN;
  const int lane = tid & 63, wid = tid >> 6;
  float v[NP];
  float mx = -1e30f;
#pragma unroll
  for (int i = 0; i < NP; ++i) { v[i] = b2f(p[tid + (i << 8)]); mx = fmaxf(mx, v[i]); }
#pragma unroll
  for (int o = 32; o > 0; o >>= 1) mx = fmaxf(mx, __shfl_xor(mx, o));
  __shared__ float red[4], red2[4];
  if (lane == 0) red[wid] = mx;
  __syncthreads();
  mx = fmaxf(fmaxf(red[0], red[1]), fmaxf(red[2], red[3]));
  float sum = 0.f;
#pragma unroll
  for (int i = 0; i < NP; ++i) { v[i] = __expf(v[i] - mx); sum += v[i]; }
#pragma unroll
  for (int o = 32; o > 0; o >>= 1) sum += __shfl_xor(sum, o);
  if (lane == 0) red2[wid] = sum;
  __syncthreads();
  sum = red2[0] + red2[1] + red2[2] + red2[3];
  const float inv = 1.f / sum;
#pragma unroll
  for (int i = 0; i < NP; ++i) p[tid + (i << 8)] = f2b(v[i] * inv);
}

// per-row: gate_t = relu(tok . W_ts + b_ts), rowsum, rowsumsq. 1 wave/row.
__global__ __launch_bounds__(256) void row_stats_k(
    const float* __restrict__ tok, const float* __restrict__ Wts,
    const float* __restrict__ bts, float* __restrict__ gate_t,
    float* __restrict__ rowsum, float* __restrict__ rowsumsq) {
  const int wid = threadIdx.x >> 6, lane = threadIdx.x & 63;
  const int row = blockIdx.x * 4 + wid;
  const float* p = tok + (size_t)row * 768;
  float s = 0.f, q = 0.f, g = 0.f;
#pragma unroll
  for (int i = 0; i < 12; ++i) {
    float t = p[lane + i * 64];
    s += t; q += t * t; g += t * Wts[lane + i * 64];
  }
#pragma unroll
  for (int o = 32; o > 0; o >>= 1) {
    s += __shfl_xor(s, o); q += __shfl_xor(q, o); g += __shfl_xor(g, o);
  }
  if (lane == 0) {
    gate_t[row] = fmaxf(g + bts[0], 0.f);
    rowsum[row] = s;
    rowsumsq[row] = q;
  }
}

// per-column: gate_f, colsum_tok, colsumsq_tok, colsum_tsgsa. grid (B,3)x256.
__global__ __launch_bounds__(256) void col_stats_k(
    const float* __restrict__ tok, const float* __restrict__ Wfs,
    const float* __restrict__ bfs, const float* __restrict__ gate_t,
    float* __restrict__ gate_f, float* __restrict__ colsum_tok,
    float* __restrict__ colsumsq_tok, float* __restrict__ colsum_tsg) {
  const int b = blockIdx.x, h = blockIdx.y * 256 + threadIdx.x;
  const float* p = tok + (size_t)b * 512 * 768 + h;
  const float* gt = gate_t + b * 512;
  float cs = 0.f, cq = 0.f, gf = 0.f, tg = 0.f;
#pragma unroll 4
  for (int s = 0; s < 512; ++s) {
    float t = p[(size_t)s * 768];
    cs += t; cq += t * t; gf += t * Wfs[s]; tg += t * gt[s];
  }
  const int idx = b * 768 + h;
  gate_f[idx] = fmaxf(gf + bfs[0], 0.f);
  colsum_tok[idx] = cs;
  colsumsq_tok[idx] = cq;
  colsum_tsg[idx] = tg;
}

// per-batch scalar stats for TSGSA and FSGSA. st: [tsg_s|tsg_q|fsg_s|fsg_q]x32
__global__ __launch_bounds__(256) void batch_stats_k(
    const float* __restrict__ gate_t, const float* __restrict__ rowsum,
    const float* __restrict__ rowsumsq, const float* __restrict__ gate_f,
    const float* __restrict__ colsum_tok, const float* __restrict__ colsumsq_tok,
    float* __restrict__ st) {
  __shared__ float red[4][256];
  const int b = blockIdx.x, tid = threadIdx.x;
  float ts = 0.f, tq = 0.f, fs = 0.f, fq = 0.f;
  for (int s = tid; s < 512; s += 256) {
    float g = gate_t[b * 512 + s];
    ts += g * rowsum[b * 512 + s];
    tq += g * g * rowsumsq[b * 512 + s];
  }
  for (int h = tid; h < 768; h += 256) {
    float g = gate_f[b * 768 + h];
    fs += g * colsum_tok[b * 768 + h];
    fq += g * g * colsumsq_tok[b * 768 + h];
  }
  red[0][tid] = ts; red[1][tid] = tq; red[2][tid] = fs; red[3][tid] = fq;
  __syncthreads();
  for (int o = 128; o > 0; o >>= 1) {
    if (tid < o) {
      red[0][tid] += red[0][tid + o];
      red[1][tid] += red[1][tid + o];
      red[2][tid] += red[2][tid + o];
      red[3][tid] += red[3][tid + o];
    }
    __syncthreads();
  }
  if (tid == 0) {
    st[b] = red[0][0]; st[32 + b] = red[1][0];
    st[64 + b] = red[2][0]; st[96 + b] = red[3][0];
  }
}

// build pooled [B, 7*768] from column sums + batch stats
__global__ __launch_bounds__(768) void pooled_k(
    const float* __restrict__ colsum_tok, const float* __restrict__ colsum_tsa,
    const float* __restrict__ bstat_tsa, const float* __restrict__ colsum_fsa,
    const float* __restrict__ bstat_fsa, const float* __restrict__ colsum_tgsa,
    const float* __restrict__ bstat_tgsa, const float* __restrict__ colsum_tsg,
    const float* __restrict__ gate_f, const float* __restrict__ st,
    float* __restrict__ pooled) {
  const int b = blockIdx.x, h = threadIdx.x;
  const float invS = 1.f / 512.f, invN = 1.f / (512.f * 768.f);
  const int i = b * 768 + h;
  float* pr = pooled + (size_t)b * 5376;
  pr[h] = colsum_tok[i] * invS;
  auto lnslot = [&](int slot, float cs, float bs, float bq) {
    float m = bs * invN;
    float var = bq * invN - m * m;
    pr[slot * 768 + h] = (cs * invS - m) * rsqrtf(var + 1e-8f);
  };
  lnslot(1, colsum_tsa[i], bstat_tsa[b], bstat_tsa[32 + b]);
  lnslot(2, colsum_fsa[i], bstat_fsa[b], bstat_fsa[32 + b]);
  lnslot(3, colsum_tgsa[i], bstat_tgsa[b], bstat_tgsa[32 + b]);
  const float fsg_cs = gate_f[i] * colsum_tok[i];
  lnslot(4, fsg_cs, st[64 + b], st[96 + b]);
  lnslot(5, colsum_tsg[i], st[b], st[32 + b]);
  lnslot(6, fsg_cs, st[64 + b], st[96 + b]);
}

// tmp1 += pooled-slice . W1-slice.  grid (6 colchunks, 42 kchunks), 256 thr.
__global__ __launch_bounds__(256) void fnn1_k(const float* __restrict__ pooled,
                                              const float* __restrict__ W1,
                                              float* __restrict__ tmp1) {
  __shared__ float sp[128][36];  // sp[j][b], padded for bank/alignment
  const int c0 = blockIdx.x << 7, k0 = blockIdx.y << 7;
  const int tid = threadIdx.x;
  for (int i = tid; i < 4096; i += 256) {
    int b = i >> 7, j = i & 127;
    sp[j][b] = pooled[(size_t)b * 5376 + k0 + j];
  }
  __syncthreads();
  const int c = c0 + (tid & 127);
  const int u = (tid >> 7) << 4;  // 0 or 16: which 16 batches
  float acc[16];
#pragma unroll
  for (int t = 0; t < 16; ++t) acc[t] = 0.f;
#pragma unroll 4
  for (int j = 0; j < 128; ++j) {
    float w = W1[(size_t)(k0 + j) * 768 + c];
    const f32x4* row = (const f32x4*)&sp[j][u];
#pragma unroll
    for (int t4 = 0; t4 < 4; ++t4) {
      f32x4 v = row[t4];
#pragma unroll
      for (int r = 0; r < 4; ++r) acc[t4 * 4 + r] += v[r] * w;
    }
  }
#pragma unroll
  for (int t = 0; t < 16; ++t) atomicAdd(&tmp1[(u + t) * 768 + c], acc[t]);
}

// out[b,c] = sum_k (tmp1[b,k]+b1[k]) * W2[k,c] + b2[c].  One wave per output.
__global__ __launch_bounds__(256) void fnn2_k(const float* __restrict__ tmp1,
                                              const float* __restrict__ b1,
                                              const float* __restrict__ W2,
                                              const float* __restrict__ b2,
                                              float* __restrict__ out) {
  const int gw = blockIdx.x * 4 + (threadIdx.x >> 6);  // 0..95
  const int lane = threadIdx.x & 63;
  const int b = gw / 3, c = gw % 3;
  float a = 0.f;
#pragma unroll
  for (int i = 0; i < 12; ++i) {
    int k = lane + i * 64;
    a += (tmp1[b * 768 + k] + b1[k]) * W2[k * 3 + c];
  }
#pragma unroll
  for (int o = 32; o > 0; o >>= 1) a += __shfl_xor(a, o);
  if (lane == 0) out[b * 3 + c] = a + b2[c];
}

extern "C" void kernel_launch(void* const* d_in, const int* in_sizes, int n_in,
                              void* d_out, int out_size, void* d_ws, size_t ws_size,
                              hipStream_t stream) {
  const float* tokens = (const float*)d_in[0];
  const float* Wq = (const float*)d_in[1];
  const float* bq = (const float*)d_in[2];
  const float* Wk = (const float*)d_in[3];
  const float* bk = (const float*)d_in[4];
  const float* Wv = (const float*)d_in[5];
  const float* bv = (const float*)d_in[6];
  const float* Wts = (const float*)d_in[7];
  const float* bts = (const float*)d_in[8];
  const float* Wfs = (const float*)d_in[9];
  const float* bfs = (const float*)d_in[10];
  const float* Wtg = (const float*)d_in[11];
  const float* btg = (const float*)d_in[12];
  const float* W1 = (const float*)d_in[13];
  const float* b1 = (const float*)d_in[14];
  const float* W2 = (const float*)d_in[15];
  const float* b2 = (const float*)d_in[16];
  float* out = (float*)d_out;

  char* ws = (char*)d_ws;
  size_t off = 0;
  auto take = [&](size_t bytes) -> char* {
    char* p = ws + off;
    off += (bytes + 255) & ~(size_t)255;
    return p;
  };
  u16* tokb = (u16*)take((size_t)16384 * 768 * 2);
  u16* WqT = (u16*)take((size_t)768 * 768 * 2);
  u16* WkT = (u16*)take((size_t)768 * 768 * 2);
  u16* WvT = (u16*)take((size_t)768 * 768 * 2);
  u16* WtgT = (u16*)take((size_t)768 * 768 * 2);
  u16* Qb = (u16*)take((size_t)16384 * 768 * 2);
  u16* Kb = (u16*)take((size_t)16384 * 768 * 2);
  u16* Vb = (u16*)take((size_t)16384 * 768 * 2);
  u16* Qt = (u16*)take((size_t)768 * 16384 * 2);
  u16* Kt = (u16*)take((size_t)768 * 16384 * 2);
  u16* Vt = (u16*)take((size_t)768 * 16384 * 2);
  u16* attb = (u16*)take((size_t)32 * 512 * 512 * 2);
  u16* attNb = (u16*)take((size_t)32 * 768 * 768 * 2);
  // --- zeroed (atomic-accumulated) region: keep contiguous ---
  char* zbase = ws + off;
  float* colsum_tsa = (float*)take(24576 * 4);
  float* colsum_fsa = (float*)take(24576 * 4);
  float* colsum_tgsa = (float*)take(24576 * 4);
  float* bstat_tsa = (float*)take(64 * 4);
  float* bstat_fsa = (float*)take(64 * 4);
  float* bstat_tgsa = (float*)take(64 * 4);
  float* tmp1 = (float*)take((size_t)32 * 768 * 4);
  size_t zbytes = (size_t)((ws + off) - zbase);
  // --- fully-overwritten buffers ---
  float* colsum_tsg = (float*)take(24576 * 4);
  float* gate_t = (float*)take(16384 * 4);
  float* rowsum = (float*)take(16384 * 4);
  float* rowsumsq = (float*)take(16384 * 4);
  float* gate_f = (float*)take(24576 * 4);
  float* colsum_tok = (float*)take(24576 * 4);
  float* colsumsq_tok = (float*)take(24576 * 4);
  float* st4 = (float*)take(128 * 4);
  float* pooled = (float*)take((size_t)32 * 5376 * 4);

  hipMemsetAsync(zbase, 0, zbytes, stream);

  const float scale = 1.0f / sqrtf(768.0f);
  const dim3 blk(256);

  // prep: tokens->bf16, weights->transposed bf16
  cvt_tok_k<<<6144, blk, 0, stream>>>(tokens, tokb);
  transpose_w_k<<<dim3(12, 12), blk, 0, stream>>>(Wq, WqT);
  transpose_w_k<<<dim3(12, 12), blk, 0, stream>>>(Wk, WkT);
  transpose_w_k<<<dim3(12, 12), blk, 0, stream>>>(Wv, WvT);
  transpose_w_k<<<dim3(12, 12), blk, 0, stream>>>(Wtg, WtgT);

  // projections: Q, K, V (store bf16 + transposed), TGSA (gated reduce)
  gemm_k<1, 1, 0, 1, 0><<<dim3(6, 128, 1), blk, 0, stream>>>(
      tokb, WqT, Qb, Qt, bq, nullptr, nullptr, nullptr, 16384, 768, 768, 768,
      768, 768, 0, 0, 0, 0.f);
  gemm_k<1, 1, 0, 1, 0><<<dim3(6, 128, 1), blk, 0, stream>>>(
      tokb, WkT, Kb, Kt, bk, nullptr, nullptr, nullptr, 16384, 768, 768, 768,
      768, 768, 0, 0, 0, 0.f);
  gemm_k<1, 1, 0, 1, 0><<<dim3(6, 128, 1), blk, 0, stream>>>(
      tokb, WvT, Vb, Vt, bv, nullptr, nullptr, nullptr, 16384, 768, 768, 768,
      768, 768, 0, 0, 0, 0.f);
  gemm_k<1, 1, 0, 1, 1><<<dim3(6, 128, 1), blk, 0, stream>>>(
      tokb, WtgT, nullptr, nullptr, btg, tokens, colsum_tgsa, bstat_tgsa, 16384,
      768, 768, 768, 768, 768, 0, 0, 0, 0.f);

  // token attention scores: att[s,t] = Q[s,:].K[t,:] * scale
  gemm_k<1, 1, 0, 1, 2><<<dim3(4, 4, 32), blk, 0, stream>>>(
      Qb, Kb, attb, nullptr, nullptr, nullptr, nullptr, nullptr, 512, 512, 768,
      768, 768, 512, 393216, 393216, 262144, scale);
  softmax_k<512><<<16384, 256, 0, stream>>>(attb);

  // feature attention scores: attN[h,g] = sum_s Q[s,h]K[s,g] * scale
  gemm_k<1, 1, 0, 1, 2><<<dim3(6, 6, 32), blk, 0, stream>>>(
      Qt, Kt, attNb, nullptr, nullptr, nullptr, nullptr, nullptr, 768, 768, 512,
      16384, 16384, 768, 512, 512, 589824, scale);
  softmax_k<768><<<24576, 256, 0, stream>>>(attNb);

  // TSA = att @ V  -> reduce only
  gemm_k<1, 1, 0, 1, 3><<<dim3(6, 4, 32), blk, 0, stream>>>(
      attb, Vt, nullptr, nullptr, nullptr, nullptr, colsum_tsa, bstat_tsa, 512,
      768, 512, 512, 16384, 0, 262144, 512, 0, 0.f);
  // FSA = V @ attN -> reduce only
  gemm_k<1, 1, 0, 0, 3><<<dim3(6, 4, 32), blk, 0, stream>>>(
      Vb, attNb, nullptr, nullptr, nullptr, nullptr, colsum_fsa, bstat_fsa, 512,
      768, 768, 768, 768, 0, 393216, 589824, 0, 0.f);

  // gate-branch statistics
  row_stats_k<<<4096, blk, 0, stream>>>(tokens, Wts, bts, gate_t, rowsum, rowsumsq);
  col_stats_k<<<dim3(32, 3), blk, 0, stream>>>(tokens, Wfs, bfs, gate_t, gate_f,
                                               colsum_tok, colsumsq_tok, colsum_tsg);
  batch_stats_k<<<32, blk, 0, stream>>>(gate_t, rowsum, rowsumsq, gate_f,
                                        colsum_tok, colsumsq_tok, st4);

  pooled_k<<<32, 768, 0, stream>>>(colsum_tok, colsum_tsa, bstat_tsa, colsum_fsa,
                                   bstat_fsa, colsum_tgsa, bstat_tgsa, colsum_tsg,
                                   gate_f, st4, pooled);
  fnn1_k<<<dim3(6, 42), blk, 0, stream>>>(pooled, W1, tmp1);
  fnn2_k<<<24, blk, 0, stream>>>(tmp1, b1, W2, b2, out);
}

// Round 3
// 470.027 us; speedup vs baseline: 1.9088x; 1.2424x over previous
//
#include <hip/hip_runtime.h>
#include <cmath>

typedef unsigned short u16;
typedef __attribute__((ext_vector_type(4))) float f32x4;
typedef __attribute__((ext_vector_type(4))) unsigned int u32x4;
typedef __attribute__((ext_vector_type(8))) __bf16 bf16x8;

__device__ __forceinline__ u16 f2b(float f) {
  unsigned int u = __builtin_bit_cast(unsigned int, f);
  return (u16)((u + 0x7fffu + ((u >> 16) & 1u)) >> 16);  // RNE
}
__device__ __forceinline__ float b2f(u16 h) {
  unsigned int u = ((unsigned int)h) << 16;
  return __builtin_bit_cast(float, u);
}

__device__ __forceinline__ void glds16(const u16* g, u16* l) {
  __builtin_amdgcn_global_load_lds(
      (const __attribute__((address_space(1))) void*)g,
      (__attribute__((address_space(3))) void*)l, 16, 0, 0);
}

// ---------------------------------------------------------------------------
// Fast bf16-MFMA GEMM, 128x128 tile, BK=32, 256 threads (4 waves, 2x2).
// A: M x K row-major bf16 (lda), per-z stride sA (elements)
// B: N x K row-major bf16 (ldb)  [i.e. B(k,n) = Bp[n*ldb+k]], stride sB
// Staging: global_load_lds width-16, double-buffered LDS, counted vmcnt.
// Block remap: bijective XCD chunking (requires nwg % 8 == 0).
// EPI: 0 = store bf16 C + bias[n]; if CpT, also store C^T packed (ldct=16384)
//      1 = TGSA reduce: v = sigmoid(acc+bias[n]) * tok[m,n]; colsum/bsum/bsumsq
//      2 = store bf16 (acc*scale)  (raw attention scores)
//      3 = reduce-only: colsum[z,n], bsum[z], bsumsq[z]
// ---------------------------------------------------------------------------
template <int EPI>
__global__ __launch_bounds__(256) void gemm_f_k(
    const u16* __restrict__ Ap, const u16* __restrict__ Bp, u16* __restrict__ Cp,
    u16* __restrict__ CpT, const float* __restrict__ bias,
    const float* __restrict__ tokp, float* __restrict__ colsum,
    float* __restrict__ bstat, int K, int lda, int ldb, int ldc, long sA,
    long sB, long sC, float scale) {
  __shared__ alignas(16) u16 smem[4][4096];  // A0,B0,A1,B1 : 128 rows x 32 u16

  // bijective XCD-chunked remap (nwg % 8 == 0 for all our grids)
  const int gx = gridDim.x, gxy = gx * gridDim.y;
  const int nwg = gxy * gridDim.z;
  int orig = (blockIdx.z * gridDim.y + blockIdx.y) * gx + blockIdx.x;
  int gwi = (orig & 7) * (nwg >> 3) + (orig >> 3);
  const int z = gwi / gxy;
  int rem = gwi - z * gxy;
  const int ty = rem / gx, tx = rem - ty * gx;
  const int tileM = ty << 7, tileN = tx << 7;

  const u16* Abase = Ap + (size_t)z * sA;
  const u16* Bbase = Bp + (size_t)z * sB;

  const int tid = threadIdx.x;
  const int lane = tid & 63, w = tid >> 6;
  const int wr = (w >> 1) << 6, wc = (w & 1) << 6;
  const int fr = lane & 15, fg = lane >> 4;

  f32x4 acc[4][4];
#pragma unroll
  for (int i = 0; i < 4; ++i)
#pragma unroll
    for (int j = 0; j < 4; ++j) acc[i][j] = (f32x4){0.f, 0.f, 0.f, 0.f};

  // staging addresses: wave w covers rows [w*32, w*32+32) of each tile
  const int srow = (w << 5) + (lane >> 2), scol = (lane & 3) << 3;
  const u16* gA = Abase + (size_t)(tileM + srow) * lda + scol;
  const u16* gB = Bbase + (size_t)(tileN + srow) * ldb + scol;
  const int ldsw = (w << 5) * 32;  // u16 offset of wave's chunk

  auto STAGE = [&](int buf, int k0) {
    const u16* ga = gA + k0;
    const u16* gb = gB + k0;
    u16* la = &smem[buf * 2][ldsw];
    u16* lb = &smem[buf * 2 + 1][ldsw];
    glds16(ga, la);
    glds16(ga + (size_t)16 * lda, la + 512);
    glds16(gb, lb);
    glds16(gb + (size_t)16 * ldb, lb + 512);
  };

  const int nt = K >> 5;
  STAGE(0, 0);
  int cur = 0;
  for (int t = 0; t < nt; ++t) {
    if (t + 1 < nt) {
      STAGE(cur ^ 1, (t + 1) << 5);
      asm volatile("s_waitcnt vmcnt(4)" ::: "memory");
    } else {
      asm volatile("s_waitcnt vmcnt(0)" ::: "memory");
    }
    __builtin_amdgcn_s_barrier();
    asm volatile("" ::: "memory");
    const u16* Ab = smem[cur * 2];
    const u16* Bb = smem[cur * 2 + 1];
    bf16x8 av[4], bw[4];
#pragma unroll
    for (int m = 0; m < 4; ++m)
      av[m] = *(const bf16x8*)&Ab[(wr + (m << 4) + fr) * 32 + (fg << 3)];
#pragma unroll
    for (int n = 0; n < 4; ++n)
      bw[n] = *(const bf16x8*)&Bb[(wc + (n << 4) + fr) * 32 + (fg << 3)];
#pragma unroll
    for (int m = 0; m < 4; ++m)
#pragma unroll
      for (int n = 0; n < 4; ++n)
        acc[m][n] =
            __builtin_amdgcn_mfma_f32_16x16x32_bf16(av[m], bw[n], acc[m][n], 0, 0, 0);
    asm volatile("" ::: "memory");
    __builtin_amdgcn_s_barrier();
    cur ^= 1;
  }

  // ---- epilogue ----
  if constexpr (EPI == 0 || EPI == 2) {
#pragma unroll
    for (int m = 0; m < 4; ++m) {
#pragma unroll
      for (int n = 0; n < 4; ++n) {
        const int gcol = tileN + wc + (n << 4) + fr;
#pragma unroll
        for (int r = 0; r < 4; ++r) {
          const int grow = tileM + wr + (m << 4) + (fg << 2) + r;
          float v = acc[m][n][r];
          if constexpr (EPI == 0) v += bias[gcol];
          else v *= scale;
          Cp[(size_t)z * sC + (size_t)grow * ldc + gcol] = f2b(v);
        }
      }
    }
    if constexpr (EPI == 0) {
      if (CpT) {  // transposed store: CpT[gcol][grow], packed 4x u16
#pragma unroll
        for (int m = 0; m < 4; ++m) {
#pragma unroll
          for (int n = 0; n < 4; ++n) {
            const int gcol = tileN + wc + (n << 4) + fr;
            const int grow0 = tileM + wr + (m << 4) + (fg << 2);
            union { u16 u[4]; unsigned long long q; } pk;
#pragma unroll
            for (int r = 0; r < 4; ++r) pk.u[r] = f2b(acc[m][n][r] + bias[gcol]);
            *(unsigned long long*)&CpT[(size_t)gcol * 16384 + grow0] = pk.q;
          }
        }
      }
    }
  } else {
    __shared__ float scol_s[128];
    __shared__ float sred[2];
    if (tid < 128) scol_s[tid] = 0.f;
    if (tid == 0) { sred[0] = 0.f; sred[1] = 0.f; }
    __syncthreads();
    float ls = 0.f, lq = 0.f;
#pragma unroll
    for (int n = 0; n < 4; ++n) {
      float cpart = 0.f;
      const int gcol = tileN + wc + (n << 4) + fr;
#pragma unroll
      for (int m = 0; m < 4; ++m) {
#pragma unroll
        for (int r = 0; r < 4; ++r) {
          float v = acc[m][n][r];
          if constexpr (EPI == 1) {
            const int grow = tileM + wr + (m << 4) + (fg << 2) + r;
            float pre = v + bias[gcol];
            float g = 1.f / (1.f + __expf(-pre));
            v = g * tokp[(size_t)grow * 768 + gcol];
          }
          cpart += v; ls += v; lq += v * v;
        }
      }
      atomicAdd(&scol_s[wc + (n << 4) + fr], cpart);
    }
    atomicAdd(&sred[0], ls);
    atomicAdd(&sred[1], lq);
    __syncthreads();
    const int b = (EPI == 1) ? (tileM >> 9) : z;
    if (tid < 128) atomicAdd(&colsum[(size_t)b * 768 + tileN + tid], scol_s[tid]);
    if (tid == 0) {
      atomicAdd(&bstat[b], sred[0]);
      atomicAdd(&bstat[32 + b], sred[1]);
    }
  }
}

// tokens f32 -> bf16, 8 elems/thread
__global__ __launch_bounds__(256) void cvt_tok_k(const float* __restrict__ in,
                                                 u16* __restrict__ out) {
  const size_t i = ((size_t)blockIdx.x * 256 + threadIdx.x) * 8;
  f32x4 a = *(const f32x4*)(in + i), b = *(const f32x4*)(in + i + 4);
  union { u16 u[8]; u32x4 q; } pk;
#pragma unroll
  for (int j = 0; j < 4; ++j) { pk.u[j] = f2b(a[j]); pk.u[4 + j] = f2b(b[j]); }
  *(u32x4*)(out + i) = pk.q;
}

// W [768][768] f32 -> WT [768][768] bf16 (transposed)
__global__ __launch_bounds__(256) void transpose_w_k(const float* __restrict__ W,
                                                     u16* __restrict__ WT) {
  __shared__ float t[64][65];
  const int r0 = blockIdx.y << 6, c0 = blockIdx.x << 6;
  for (int i = threadIdx.x; i < 4096; i += 256) {
    int r = i >> 6, c = i & 63;
    t[r][c] = W[(size_t)(r0 + r) * 768 + c0 + c];
  }
  __syncthreads();
  for (int i = threadIdx.x; i < 4096; i += 256) {
    int rr = i >> 6, cc = i & 63;
    WT[(size_t)(c0 + rr) * 768 + r0 + cc] = f2b(t[cc][rr]);
  }
}

// bf16 [768][768] per-batch transpose (for attN -> attNt)
__global__ __launch_bounds__(256) void transpose_bf_k(const u16* __restrict__ in,
                                                      u16* __restrict__ out) {
  __shared__ u16 t[64][72];
  const size_t base = (size_t)blockIdx.z * 589824;
  const int r0 = blockIdx.y << 6, c0 = blockIdx.x << 6;
  for (int i = threadIdx.x; i < 512; i += 256) {
    int r = i >> 3, c8 = (i & 7) << 3;
    union { u32x4 q; u16 u[8]; } pk;
    pk.q = *(const u32x4*)&in[base + (size_t)(r0 + r) * 768 + c0 + c8];
#pragma unroll
    for (int j = 0; j < 8; ++j) t[c8 + j][r] = pk.u[j];
  }
  __syncthreads();
  for (int i = threadIdx.x; i < 512; i += 256) {
    int r = i >> 3, c8 = (i & 7) << 3;
    *(u32x4*)&out[base + (size_t)(c0 + r) * 768 + r0 + c8] = *(u32x4*)&t[r][c8];
  }
}

// in-place row softmax on bf16 scores; block=256, grid=numRows
template <int LEN>
__global__ __launch_bounds__(256) void softmax_k(u16* __restrict__ data) {
  constexpr int NP = LEN / 256;
  const int row = blockIdx.x, tid = threadIdx.x;
  u16* p = data + (size_t)row * LEN;
  const int lane = tid & 63, wid = tid >> 6;
  float v[NP];
  float mx = -1e30f;
#pragma unroll
  for (int i = 0; i < NP; ++i) { v[i] = b2f(p[tid + (i << 8)]); mx = fmaxf(mx, v[i]); }
#pragma unroll
  for (int o = 32; o > 0; o >>= 1) mx = fmaxf(mx, __shfl_xor(mx, o));
  __shared__ float red[4], red2[4];
  if (lane == 0) red[wid] = mx;
  __syncthreads();
  mx = fmaxf(fmaxf(red[0], red[1]), fmaxf(red[2], red[3]));
  float sum = 0.f;
#pragma unroll
  for (int i = 0; i < NP; ++i) { v[i] = __expf(v[i] - mx); sum += v[i]; }
#pragma unroll
  for (int o = 32; o > 0; o >>= 1) sum += __shfl_xor(sum, o);
  if (lane == 0) red2[wid] = sum;
  __syncthreads();
  sum = red2[0] + red2[1] + red2[2] + red2[3];
  const float inv = 1.f / sum;
#pragma unroll
  for (int i = 0; i < NP; ++i) p[tid + (i << 8)] = f2b(v[i] * inv);
}

// per-row: gate_t = relu(tok . W_ts + b_ts), rowsum, rowsumsq. 1 wave/row.
__global__ __launch_bounds__(256) void row_stats_k(
    const float* __restrict__ tok, const float* __restrict__ Wts,
    const float* __restrict__ bts, float* __restrict__ gate_t,
    float* __restrict__ rowsum, float* __restrict__ rowsumsq) {
  const int wid = threadIdx.x >> 6, lane = threadIdx.x & 63;
  const int row = blockIdx.x * 4 + wid;
  const float* p = tok + (size_t)row * 768;
  float s = 0.f, q = 0.f, g = 0.f;
#pragma unroll
  for (int i = 0; i < 12; ++i) {
    float t = p[lane + i * 64];
    s += t; q += t * t; g += t * Wts[lane + i * 64];
  }
#pragma unroll
  for (int o = 32; o > 0; o >>= 1) {
    s += __shfl_xor(s, o); q += __shfl_xor(q, o); g += __shfl_xor(g, o);
  }
  if (lane == 0) {
    gate_t[row] = fmaxf(g + bts[0], 0.f);
    rowsum[row] = s;
    rowsumsq[row] = q;
  }
}

// per-column: gate_f, colsum_tok, colsumsq_tok, colsum_tsgsa. grid (B,3)x256.
__global__ __launch_bounds__(256) void col_stats_k(
    const float* __restrict__ tok, const float* __restrict__ Wfs,
    const float* __restrict__ bfs, const float* __restrict__ gate_t,
    float* __restrict__ gate_f, float* __restrict__ colsum_tok,
    float* __restrict__ colsumsq_tok, float* __restrict__ colsum_tsg) {
  const int b = blockIdx.x, h = blockIdx.y * 256 + threadIdx.x;
  const float* p = tok + (size_t)b * 512 * 768 + h;
  const float* gt = gate_t + b * 512;
  float cs = 0.f, cq = 0.f, gf = 0.f, tg = 0.f;
#pragma unroll 4
  for (int s = 0; s < 512; ++s) {
    float t = p[(size_t)s * 768];
    cs += t; cq += t * t; gf += t * Wfs[s]; tg += t * gt[s];
  }
  const int idx = b * 768 + h;
  gate_f[idx] = fmaxf(gf + bfs[0], 0.f);
  colsum_tok[idx] = cs;
  colsumsq_tok[idx] = cq;
  colsum_tsg[idx] = tg;
}

// per-batch scalar stats for TSGSA and FSGSA. st: [tsg_s|tsg_q|fsg_s|fsg_q]x32
__global__ __launch_bounds__(256) void batch_stats_k(
    const float* __restrict__ gate_t, const float* __restrict__ rowsum,
    const float* __restrict__ rowsumsq, const float* __restrict__ gate_f,
    const float* __restrict__ colsum_tok, const float* __restrict__ colsumsq_tok,
    float* __restrict__ st) {
  __shared__ float red[4][256];
  const int b = blockIdx.x, tid = threadIdx.x;
  float ts = 0.f, tq = 0.f, fs = 0.f, fq = 0.f;
  for (int s = tid; s < 512; s += 256) {
    float g = gate_t[b * 512 + s];
    ts += g * rowsum[b * 512 + s];
    tq += g * g * rowsumsq[b * 512 + s];
  }
  for (int h = tid; h < 768; h += 256) {
    float g = gate_f[b * 768 + h];
    fs += g * colsum_tok[b * 768 + h];
    fq += g * g * colsumsq_tok[b * 768 + h];
  }
  red[0][tid] = ts; red[1][tid] = tq; red[2][tid] = fs; red[3][tid] = fq;
  __syncthreads();
  for (int o = 128; o > 0; o >>= 1) {
    if (tid < o) {
      red[0][tid] += red[0][tid + o];
      red[1][tid] += red[1][tid + o];
      red[2][tid] += red[2][tid + o];
      red[3][tid] += red[3][tid + o];
    }
    __syncthreads();
  }
  if (tid == 0) {
    st[b] = red[0][0]; st[32 + b] = red[1][0];
    st[64 + b] = red[2][0]; st[96 + b] = red[3][0];
  }
}

// build pooled [B, 7*768] from column sums + batch stats
__global__ __launch_bounds__(768) void pooled_k(
    const float* __restrict__ colsum_tok, const float* __restrict__ colsum_tsa,
    const float* __restrict__ bstat_tsa, const float* __restrict__ colsum_fsa,
    const float* __restrict__ bstat_fsa, const float* __restrict__ colsum_tgsa,
    const float* __restrict__ bstat_tgsa, const float* __restrict__ colsum_tsg,
    const float* __restrict__ gate_f, const float* __restrict__ st,
    float* __restrict__ pooled) {
  const int b = blockIdx.x, h = threadIdx.x;
  const float invS = 1.f / 512.f, invN = 1.f / (512.f * 768.f);
  const int i = b * 768 + h;
  float* pr = pooled + (size_t)b * 5376;
  pr[h] = colsum_tok[i] * invS;
  auto lnslot = [&](int slot, float cs, float bs, float bq) {
    float m = bs * invN;
    float var = bq * invN - m * m;
    pr[slot * 768 + h] = (cs * invS - m) * rsqrtf(var + 1e-8f);
  };
  lnslot(1, colsum_tsa[i], bstat_tsa[b], bstat_tsa[32 + b]);
  lnslot(2, colsum_fsa[i], bstat_fsa[b], bstat_fsa[32 + b]);
  lnslot(3, colsum_tgsa[i], bstat_tgsa[b], bstat_tgsa[32 + b]);
  const float fsg_cs = gate_f[i] * colsum_tok[i];
  lnslot(4, fsg_cs, st[64 + b], st[96 + b]);
  lnslot(5, colsum_tsg[i], st[b], st[32 + b]);
  lnslot(6, fsg_cs, st[64 + b], st[96 + b]);
}

// tmp1 += pooled-slice . W1-slice.  grid (6 colchunks, 42 kchunks), 256 thr.
__global__ __launch_bounds__(256) void fnn1_k(const float* __restrict__ pooled,
                                              const float* __restrict__ W1,
                                              float* __restrict__ tmp1) {
  __shared__ float sp[128][36];
  const int c0 = blockIdx.x << 7, k0 = blockIdx.y << 7;
  const int tid = threadIdx.x;
  for (int i = tid; i < 4096; i += 256) {
    int b = i >> 7, j = i & 127;
    sp[j][b] = pooled[(size_t)b * 5376 + k0 + j];
  }
  __syncthreads();
  const int c = c0 + (tid & 127);
  const int u = (tid >> 7) << 4;
  float acc[16];
#pragma unroll
  for (int t = 0; t < 16; ++t) acc[t] = 0.f;
#pragma unroll 4
  for (int j = 0; j < 128; ++j) {
    float w = W1[(size_t)(k0 + j) * 768 + c];
    const f32x4* row = (const f32x4*)&sp[j][u];
#pragma unroll
    for (int t4 = 0; t4 < 4; ++t4) {
      f32x4 v = row[t4];
#pragma unroll
      for (int r = 0; r < 4; ++r) acc[t4 * 4 + r] += v[r] * w;
    }
  }
#pragma unroll
  for (int t = 0; t < 16; ++t) atomicAdd(&tmp1[(u + t) * 768 + c], acc[t]);
}

// out[b,c] = sum_k (tmp1[b,k]+b1[k]) * W2[k,c] + b2[c].  One wave per output.
__global__ __launch_bounds__(256) void fnn2_k(const float* __restrict__ tmp1,
                                              const float* __restrict__ b1,
                                              const float* __restrict__ W2,
                                              const float* __restrict__ b2,
                                              float* __restrict__ out) {
  const int gw = blockIdx.x * 4 + (threadIdx.x >> 6);
  const int lane = threadIdx.x & 63;
  const int b = gw / 3, c = gw % 3;
  float a = 0.f;
#pragma unroll
  for (int i = 0; i < 12; ++i) {
    int k = lane + i * 64;
    a += (tmp1[b * 768 + k] + b1[k]) * W2[k * 3 + c];
  }
#pragma unroll
  for (int o = 32; o > 0; o >>= 1) a += __shfl_xor(a, o);
  if (lane == 0) out[b * 3 + c] = a + b2[c];
}

extern "C" void kernel_launch(void* const* d_in, const int* in_sizes, int n_in,
                              void* d_out, int out_size, void* d_ws, size_t ws_size,
                              hipStream_t stream) {
  const float* tokens = (const float*)d_in[0];
  const float* Wq = (const float*)d_in[1];
  const float* bq = (const float*)d_in[2];
  const float* Wk = (const float*)d_in[3];
  const float* bk = (const float*)d_in[4];
  const float* Wv = (const float*)d_in[5];
  const float* bv = (const float*)d_in[6];
  const float* Wts = (const float*)d_in[7];
  const float* bts = (const float*)d_in[8];
  const float* Wfs = (const float*)d_in[9];
  const float* bfs = (const float*)d_in[10];
  const float* Wtg = (const float*)d_in[11];
  const float* btg = (const float*)d_in[12];
  const float* W1 = (const float*)d_in[13];
  const float* b1 = (const float*)d_in[14];
  const float* W2 = (const float*)d_in[15];
  const float* b2 = (const float*)d_in[16];
  float* out = (float*)d_out;

  char* ws = (char*)d_ws;
  size_t off = 0;
  auto take = [&](size_t bytes) -> char* {
    char* p = ws + off;
    off += (bytes + 255) & ~(size_t)255;
    return p;
  };
  u16* tokb = (u16*)take((size_t)16384 * 768 * 2);
  u16* WqT = (u16*)take((size_t)768 * 768 * 2);
  u16* WkT = (u16*)take((size_t)768 * 768 * 2);
  u16* WvT = (u16*)take((size_t)768 * 768 * 2);
  u16* WtgT = (u16*)take((size_t)768 * 768 * 2);
  u16* Qb = (u16*)take((size_t)16384 * 768 * 2);
  u16* Kb = (u16*)take((size_t)16384 * 768 * 2);
  u16* Vb = (u16*)take((size_t)16384 * 768 * 2);
  u16* Qt = (u16*)take((size_t)768 * 16384 * 2);
  u16* Kt = (u16*)take((size_t)768 * 16384 * 2);
  u16* Vt = (u16*)take((size_t)768 * 16384 * 2);
  u16* attb = (u16*)take((size_t)32 * 512 * 512 * 2);
  u16* attNb = (u16*)take((size_t)32 * 768 * 768 * 2);
  // attNt aliases Qt+Kt (both dead after the attN-score GEMM; 50.3MB >= 37.7MB)
  u16* attNt = Qt;
  // --- zeroed (atomic-accumulated) region: keep contiguous ---
  char* zbase = ws + off;
  float* colsum_tsa = (float*)take(24576 * 4);
  float* colsum_fsa = (float*)take(24576 * 4);
  float* colsum_tgsa = (float*)take(24576 * 4);
  float* bstat_tsa = (float*)take(64 * 4);
  float* bstat_fsa = (float*)take(64 * 4);
  float* bstat_tgsa = (float*)take(64 * 4);
  float* tmp1 = (float*)take((size_t)32 * 768 * 4);
  size_t zbytes = (size_t)((ws + off) - zbase);
  // --- fully-overwritten buffers ---
  float* colsum_tsg = (float*)take(24576 * 4);
  float* gate_t = (float*)take(16384 * 4);
  float* rowsum = (float*)take(16384 * 4);
  float* rowsumsq = (float*)take(16384 * 4);
  float* gate_f = (float*)take(24576 * 4);
  float* colsum_tok = (float*)take(24576 * 4);
  float* colsumsq_tok = (float*)take(24576 * 4);
  float* st4 = (float*)take(128 * 4);
  float* pooled = (float*)take((size_t)32 * 5376 * 4);

  hipMemsetAsync(zbase, 0, zbytes, stream);

  const float scale = 1.0f / sqrtf(768.0f);
  const dim3 blk(256);

  // prep: tokens->bf16, weights->transposed bf16
  cvt_tok_k<<<6144, blk, 0, stream>>>(tokens, tokb);
  transpose_w_k<<<dim3(12, 12), blk, 0, stream>>>(Wq, WqT);
  transpose_w_k<<<dim3(12, 12), blk, 0, stream>>>(Wk, WkT);
  transpose_w_k<<<dim3(12, 12), blk, 0, stream>>>(Wv, WvT);
  transpose_w_k<<<dim3(12, 12), blk, 0, stream>>>(Wtg, WtgT);

  // projections: Q, K, V (store bf16 + transposed), TGSA (gated reduce)
  gemm_f_k<0><<<dim3(6, 128, 1), blk, 0, stream>>>(
      tokb, WqT, Qb, Qt, bq, nullptr, nullptr, nullptr, 768, 768, 768, 768, 0,
      0, 0, 0.f);
  gemm_f_k<0><<<dim3(6, 128, 1), blk, 0, stream>>>(
      tokb, WkT, Kb, Kt, bk, nullptr, nullptr, nullptr, 768, 768, 768, 768, 0,
      0, 0, 0.f);
  gemm_f_k<0><<<dim3(6, 128, 1), blk, 0, stream>>>(
      tokb, WvT, Vb, Vt, bv, nullptr, nullptr, nullptr, 768, 768, 768, 768, 0,
      0, 0, 0.f);
  gemm_f_k<1><<<dim3(6, 128, 1), blk, 0, stream>>>(
      tokb, WtgT, nullptr, nullptr, btg, tokens, colsum_tgsa, bstat_tgsa, 768,
      768, 768, 0, 0, 0, 0, 0.f);

  // feature attention scores first (so Qt/Kt die before attNt aliases them)
  gemm_f_k<2><<<dim3(6, 6, 32), blk, 0, stream>>>(
      Qt, Kt, attNb, nullptr, nullptr, nullptr, nullptr, nullptr, 512, 16384,
      16384, 768, 512, 512, 589824, scale);
  softmax_k<768><<<24576, 256, 0, stream>>>(attNb);
  transpose_bf_k<<<dim3(12, 12, 32), blk, 0, stream>>>(attNb, attNt);

  // token attention scores: att[s,t] = Q[s,:].K[t,:] * scale
  gemm_f_k<2><<<dim3(4, 4, 32), blk, 0, stream>>>(
      Qb, Kb, attb, nullptr, nullptr, nullptr, nullptr, nullptr, 768, 768, 768,
      512, 393216, 393216, 262144, scale);
  softmax_k<512><<<16384, 256, 0, stream>>>(attb);

  // TSA = att @ V  -> reduce only
  gemm_f_k<3><<<dim3(6, 4, 32), blk, 0, stream>>>(
      attb, Vt, nullptr, nullptr, nullptr, nullptr, colsum_tsa, bstat_tsa, 512,
      512, 16384, 0, 262144, 512, 0, 0.f);
  // FSA = V @ attN -> reduce only  (B = attN^T rows)
  gemm_f_k<3><<<dim3(6, 4, 32), blk, 0, stream>>>(
      Vb, attNt, nullptr, nullptr, nullptr, nullptr, colsum_fsa, bstat_fsa, 768,
      768, 768, 0, 393216, 589824, 0, 0.f);

  // gate-branch statistics
  row_stats_k<<<4096, blk, 0, stream>>>(tokens, Wts, bts, gate_t, rowsum, rowsumsq);
  col_stats_k<<<dim3(32, 3), blk, 0, stream>>>(tokens, Wfs, bfs, gate_t, gate_f,
                                               colsum_tok, colsumsq_tok, colsum_tsg);
  batch_stats_k<<<32, blk, 0, stream>>>(gate_t, rowsum, rowsumsq, gate_f,
                                        colsum_tok, colsumsq_tok, st4);

  pooled_k<<<32, 768, 0, stream>>>(colsum_tok, colsum_tsa, bstat_tsa, colsum_fsa,
                                   bstat_fsa, colsum_tgsa, bstat_tgsa, colsum_tsg,
                                   gate_f, st4, pooled);
  fnn1_k<<<dim3(6, 42), blk, 0, stream>>>(pooled, W1, tmp1);
  fnn2_k<<<24, blk, 0, stream>>>(tmp1, b1, W2, b2, out);
}

// Round 4
// 464.259 us; speedup vs baseline: 1.9325x; 1.0124x over previous
//
#include <hip/hip_runtime.h>
#include <cmath>

typedef unsigned short u16;
typedef __attribute__((ext_vector_type(4))) float f32x4;
typedef __attribute__((ext_vector_type(4))) unsigned int u32x4;
typedef __attribute__((ext_vector_type(8))) __bf16 bf16x8;

__device__ __forceinline__ u16 f2b(float f) {
  unsigned int u = __builtin_bit_cast(unsigned int, f);
  return (u16)((u + 0x7fffu + ((u >> 16) & 1u)) >> 16);  // RNE
}
__device__ __forceinline__ float b2f(u16 h) {
  unsigned int u = ((unsigned int)h) << 16;
  return __builtin_bit_cast(float, u);
}

__device__ __forceinline__ void glds16(const u16* g, u16* l) {
  __builtin_amdgcn_global_load_lds(
      (const __attribute__((address_space(1))) void*)g,
      (__attribute__((address_space(3))) void*)l, 16, 0, 0);
}

// ---------------------------------------------------------------------------
// Fast bf16-MFMA GEMM, 128x128 tile, BK=32, 256 threads (4 waves, 2x2).
// A: M x K row-major bf16 (lda), per-z stride sA (elements)
// B: N x K row-major bf16 (ldb)  [i.e. B(k,n) = Bp[n*ldb+k]], stride sB
// Staging: global_load_lds w16, double-buffered, counted vmcnt, LDS chunk
// swizzle (chunk ^= (row>>1)&3) applied on BOTH global-src and ds_read sides.
// Block remap: bijective XCD chunking (requires nwg % 8 == 0).
// EPI: 0 = fused QKV store: C/CT split into 768-col buffers (stride sC both)
//      1 = TGSA reduce: v = sigmoid(acc+bias[n]) * tok[m,n]; colsum/bsum/bsumsq
//      2 = store bf16 (acc*scale)  (raw attention scores)
//      3 = reduce-only: colsum[z,n], bsum[z], bsumsq[z]
// ---------------------------------------------------------------------------
template <int EPI>
__global__ __launch_bounds__(256) void gemm_f_k(
    const u16* __restrict__ Ap, const u16* __restrict__ Bp, u16* __restrict__ Cp,
    u16* __restrict__ CpT, const float* __restrict__ bias,
    const float* __restrict__ tokp, float* __restrict__ colsum,
    float* __restrict__ bstat, int K, int lda, int ldb, int ldc, long sA,
    long sB, long sC, float scale) {
  __shared__ alignas(16) u16 smem[4][4096];  // A0,B0,A1,B1 : 128 rows x 32 u16

  // bijective XCD-chunked remap (nwg % 8 == 0 for all our grids)
  const int gx = gridDim.x, gxy = gx * gridDim.y;
  const int nwg = gxy * gridDim.z;
  int orig = (blockIdx.z * gridDim.y + blockIdx.y) * gx + blockIdx.x;
  int gwi = (orig & 7) * (nwg >> 3) + (orig >> 3);
  const int z = gwi / gxy;
  int rem = gwi - z * gxy;
  const int ty = rem / gx, tx = rem - ty * gx;
  const int tileM = ty << 7, tileN = tx << 7;

  const u16* Abase = Ap + (size_t)z * sA;
  const u16* Bbase = Bp + (size_t)z * sB;

  const int tid = threadIdx.x;
  const int lane = tid & 63, w = tid >> 6;
  const int wr = (w >> 1) << 6, wc = (w & 1) << 6;
  const int fr = lane & 15, fg = lane >> 4;

  f32x4 acc[4][4];
#pragma unroll
  for (int i = 0; i < 4; ++i)
#pragma unroll
    for (int j = 0; j < 4; ++j) acc[i][j] = (f32x4){0.f, 0.f, 0.f, 0.f};

  // staging: wave w covers rows [w*32, w*32+32); global col chunk pre-swizzled
  const int srow = (w << 5) + (lane >> 2);
  const int scol = (((lane & 3) ^ ((lane >> 3) & 3)) << 3);
  const u16* gA = Abase + (size_t)(tileM + srow) * lda + scol;
  const u16* gB = Bbase + (size_t)(tileN + srow) * ldb + scol;
  const int ldsw = (w << 5) * 32;  // u16 offset of wave's chunk

  auto STAGE = [&](int buf, int k0) {
    const u16* ga = gA + k0;
    const u16* gb = gB + k0;
    u16* la = &smem[buf * 2][ldsw];
    u16* lb = &smem[buf * 2 + 1][ldsw];
    glds16(ga, la);
    glds16(ga + (size_t)16 * lda, la + 512);
    glds16(gb, lb);
    glds16(gb + (size_t)16 * ldb, lb + 512);
  };

  // ds_read swizzle: logical chunk fg of row R lives at chunk fg ^ ((R>>1)&3);
  // (R>>1)&3 == (fr>>1)&3 for all our row offsets (multiples of 16).
  const int col_off = ((fg ^ ((fr >> 1) & 3)) << 3);

  const int nt = K >> 5;
  STAGE(0, 0);
  int cur = 0;
  for (int t = 0; t < nt; ++t) {
    if (t + 1 < nt) {
      STAGE(cur ^ 1, (t + 1) << 5);
      asm volatile("s_waitcnt vmcnt(4)" ::: "memory");
    } else {
      asm volatile("s_waitcnt vmcnt(0)" ::: "memory");
    }
    __builtin_amdgcn_s_barrier();
    asm volatile("" ::: "memory");
    const u16* Ab = smem[cur * 2];
    const u16* Bb = smem[cur * 2 + 1];
    bf16x8 av[4], bw[4];
#pragma unroll
    for (int m = 0; m < 4; ++m)
      av[m] = *(const bf16x8*)&Ab[(wr + (m << 4) + fr) * 32 + col_off];
#pragma unroll
    for (int n = 0; n < 4; ++n)
      bw[n] = *(const bf16x8*)&Bb[(wc + (n << 4) + fr) * 32 + col_off];
#pragma unroll
    for (int m = 0; m < 4; ++m)
#pragma unroll
      for (int n = 0; n < 4; ++n)
        acc[m][n] =
            __builtin_amdgcn_mfma_f32_16x16x32_bf16(av[m], bw[n], acc[m][n], 0, 0, 0);
    asm volatile("" ::: "memory");
    __builtin_amdgcn_s_barrier();
    cur ^= 1;
  }

  // ---- epilogue ----
  if constexpr (EPI == 0 || EPI == 2) {
    int cbuf = 0, nbase = tileN;
    if constexpr (EPI == 0) { cbuf = tileN / 768; nbase = tileN - cbuf * 768; }
    u16* Cz = Cp + (EPI == 0 ? (size_t)cbuf * sC : (size_t)z * sC);
#pragma unroll
    for (int m = 0; m < 4; ++m) {
#pragma unroll
      for (int n = 0; n < 4; ++n) {
        const int gcol = tileN + wc + (n << 4) + fr;
        const int lcol = nbase + wc + (n << 4) + fr;
#pragma unroll
        for (int r = 0; r < 4; ++r) {
          const int grow = tileM + wr + (m << 4) + (fg << 2) + r;
          float v = acc[m][n][r];
          if constexpr (EPI == 0) v += bias[gcol];
          else v *= scale;
          Cz[(size_t)grow * ldc + lcol] = f2b(v);
        }
      }
    }
    if constexpr (EPI == 0) {
      u16* Ct = CpT + (size_t)cbuf * sC;  // Qt/Kt/Vt stride == Qb stride
#pragma unroll
      for (int m = 0; m < 4; ++m) {
#pragma unroll
        for (int n = 0; n < 4; ++n) {
          const int gcol = tileN + wc + (n << 4) + fr;
          const int lcol = nbase + wc + (n << 4) + fr;
          const int grow0 = tileM + wr + (m << 4) + (fg << 2);
          union { u16 u[4]; unsigned long long q; } pk;
#pragma unroll
          for (int r = 0; r < 4; ++r) pk.u[r] = f2b(acc[m][n][r] + bias[gcol]);
          *(unsigned long long*)&Ct[(size_t)lcol * 16384 + grow0] = pk.q;
        }
      }
    }
  } else {
    __shared__ float scol_s[128];
    __shared__ float sred[2];
    if (tid < 128) scol_s[tid] = 0.f;
    if (tid == 0) { sred[0] = 0.f; sred[1] = 0.f; }
    __syncthreads();
    float ls = 0.f, lq = 0.f;
#pragma unroll
    for (int n = 0; n < 4; ++n) {
      float cpart = 0.f;
      const int gcol = tileN + wc + (n << 4) + fr;
#pragma unroll
      for (int m = 0; m < 4; ++m) {
#pragma unroll
        for (int r = 0; r < 4; ++r) {
          float v = acc[m][n][r];
          if constexpr (EPI == 1) {
            const int grow = tileM + wr + (m << 4) + (fg << 2) + r;
            float pre = v + bias[gcol];
            float g = 1.f / (1.f + __expf(-pre));
            v = g * tokp[(size_t)grow * 768 + gcol];
          }
          cpart += v; ls += v; lq += v * v;
        }
      }
      atomicAdd(&scol_s[wc + (n << 4) + fr], cpart);
    }
    atomicAdd(&sred[0], ls);
    atomicAdd(&sred[1], lq);
    __syncthreads();
    const int b = (EPI == 1) ? (tileM >> 9) : z;
    if (tid < 128) atomicAdd(&colsum[(size_t)b * 768 + tileN + tid], scol_s[tid]);
    if (tid == 0) {
      atomicAdd(&bstat[b], sred[0]);
      atomicAdd(&bstat[32 + b], sred[1]);
    }
  }
}

// tokens f32 -> bf16, 8 elems/thread
__global__ __launch_bounds__(256) void cvt_tok_k(const float* __restrict__ in,
                                                 u16* __restrict__ out) {
  const size_t i = ((size_t)blockIdx.x * 256 + threadIdx.x) * 8;
  f32x4 a = *(const f32x4*)(in + i), b = *(const f32x4*)(in + i + 4);
  union { u16 u[8]; u32x4 q; } pk;
#pragma unroll
  for (int j = 0; j < 4; ++j) { pk.u[j] = f2b(a[j]); pk.u[4 + j] = f2b(b[j]); }
  *(u32x4*)(out + i) = pk.q;
}

// W [768][768] f32 -> WT [768][768] bf16 (transposed)
__global__ __launch_bounds__(256) void transpose_w_k(const float* __restrict__ W,
                                                     u16* __restrict__ WT) {
  __shared__ float t[64][65];
  const int r0 = blockIdx.y << 6, c0 = blockIdx.x << 6;
  for (int i = threadIdx.x; i < 4096; i += 256) {
    int r = i >> 6, c = i & 63;
    t[r][c] = W[(size_t)(r0 + r) * 768 + c0 + c];
  }
  __syncthreads();
  for (int i = threadIdx.x; i < 4096; i += 256) {
    int rr = i >> 6, cc = i & 63;
    WT[(size_t)(c0 + rr) * 768 + r0 + cc] = f2b(t[cc][rr]);
  }
}

// bf16 [768][768] per-batch transpose (for attN -> attNt)
__global__ __launch_bounds__(256) void transpose_bf_k(const u16* __restrict__ in,
                                                      u16* __restrict__ out) {
  __shared__ u16 t[64][72];
  const size_t base = (size_t)blockIdx.z * 589824;
  const int r0 = blockIdx.y << 6, c0 = blockIdx.x << 6;
  for (int i = threadIdx.x; i < 512; i += 256) {
    int r = i >> 3, c8 = (i & 7) << 3;
    union { u32x4 q; u16 u[8]; } pk;
    pk.q = *(const u32x4*)&in[base + (size_t)(r0 + r) * 768 + c0 + c8];
#pragma unroll
    for (int j = 0; j < 8; ++j) t[c8 + j][r] = pk.u[j];
  }
  __syncthreads();
  for (int i = threadIdx.x; i < 512; i += 256) {
    int r = i >> 3, c8 = (i & 7) << 3;
    *(u32x4*)&out[base + (size_t)(c0 + r) * 768 + r0 + c8] = *(u32x4*)&t[r][c8];
  }
}

// in-place row softmax on bf16 scores; block=256, grid=numRows
template <int LEN>
__global__ __launch_bounds__(256) void softmax_k(u16* __restrict__ data) {
  constexpr int NP = LEN / 256;
  const int row = blockIdx.x, tid = threadIdx.x;
  u16* p = data + (size_t)row * LEN;
  const int lane = tid & 63, wid = tid >> 6;
  float v[NP];
  float mx = -1e30f;
#pragma unroll
  for (int i = 0; i < NP; ++i) { v[i] = b2f(p[tid + (i << 8)]); mx = fmaxf(mx, v[i]); }
#pragma unroll
  for (int o = 32; o > 0; o >>= 1) mx = fmaxf(mx, __shfl_xor(mx, o));
  __shared__ float red[4], red2[4];
  if (lane == 0) red[wid] = mx;
  __syncthreads();
  mx = fmaxf(fmaxf(red[0], red[1]), fmaxf(red[2], red[3]));
  float sum = 0.f;
#pragma unroll
  for (int i = 0; i < NP; ++i) { v[i] = __expf(v[i] - mx); sum += v[i]; }
#pragma unroll
  for (int o = 32; o > 0; o >>= 1) sum += __shfl_xor(sum, o);
  if (lane == 0) red2[wid] = sum;
  __syncthreads();
  sum = red2[0] + red2[1] + red2[2] + red2[3];
  const float inv = 1.f / sum;
#pragma unroll
  for (int i = 0; i < NP; ++i) p[tid + (i << 8)] = f2b(v[i] * inv);
}

// per-row: gate_t = relu(tok . W_ts + b_ts), rowsum, rowsumsq. 1 wave/row.
__global__ __launch_bounds__(256) void row_stats_k(
    const float* __restrict__ tok, const float* __restrict__ Wts,
    const float* __restrict__ bts, float* __restrict__ gate_t,
    float* __restrict__ rowsum, float* __restrict__ rowsumsq) {
  const int wid = threadIdx.x >> 6, lane = threadIdx.x & 63;
  const int row = blockIdx.x * 4 + wid;
  const float* p = tok + (size_t)row * 768;
  float s = 0.f, q = 0.f, g = 0.f;
#pragma unroll
  for (int i = 0; i < 12; ++i) {
    float t = p[lane + i * 64];
    s += t; q += t * t; g += t * Wts[lane + i * 64];
  }
#pragma unroll
  for (int o = 32; o > 0; o >>= 1) {
    s += __shfl_xor(s, o); q += __shfl_xor(q, o); g += __shfl_xor(g, o);
  }
  if (lane == 0) {
    gate_t[row] = fmaxf(g + bts[0], 0.f);
    rowsum[row] = s;
    rowsumsq[row] = q;
  }
}

// per-column: gate_f, colsum_tok, colsumsq_tok, colsum_tsgsa. grid (B,3)x256.
__global__ __launch_bounds__(256) void col_stats_k(
    const float* __restrict__ tok, const float* __restrict__ Wfs,
    const float* __restrict__ bfs, const float* __restrict__ gate_t,
    float* __restrict__ gate_f, float* __restrict__ colsum_tok,
    float* __restrict__ colsumsq_tok, float* __restrict__ colsum_tsg) {
  const int b = blockIdx.x, h = blockIdx.y * 256 + threadIdx.x;
  const float* p = tok + (size_t)b * 512 * 768 + h;
  const float* gt = gate_t + b * 512;
  float cs = 0.f, cq = 0.f, gf = 0.f, tg = 0.f;
#pragma unroll 4
  for (int s = 0; s < 512; ++s) {
    float t = p[(size_t)s * 768];
    cs += t; cq += t * t; gf += t * Wfs[s]; tg += t * gt[s];
  }
  const int idx = b * 768 + h;
  gate_f[idx] = fmaxf(gf + bfs[0], 0.f);
  colsum_tok[idx] = cs;
  colsumsq_tok[idx] = cq;
  colsum_tsg[idx] = tg;
}

// per-batch scalar stats for TSGSA and FSGSA. st: [tsg_s|tsg_q|fsg_s|fsg_q]x32
__global__ __launch_bounds__(256) void batch_stats_k(
    const float* __restrict__ gate_t, const float* __restrict__ rowsum,
    const float* __restrict__ rowsumsq, const float* __restrict__ gate_f,
    const float* __restrict__ colsum_tok, const float* __restrict__ colsumsq_tok,
    float* __restrict__ st) {
  __shared__ float red[4][256];
  const int b = blockIdx.x, tid = threadIdx.x;
  float ts = 0.f, tq = 0.f, fs = 0.f, fq = 0.f;
  for (int s = tid; s < 512; s += 256) {
    float g = gate_t[b * 512 + s];
    ts += g * rowsum[b * 512 + s];
    tq += g * g * rowsumsq[b * 512 + s];
  }
  for (int h = tid; h < 768; h += 256) {
    float g = gate_f[b * 768 + h];
    fs += g * colsum_tok[b * 768 + h];
    fq += g * g * colsumsq_tok[b * 768 + h];
  }
  red[0][tid] = ts; red[1][tid] = tq; red[2][tid] = fs; red[3][tid] = fq;
  __syncthreads();
  for (int o = 128; o > 0; o >>= 1) {
    if (tid < o) {
      red[0][tid] += red[0][tid + o];
      red[1][tid] += red[1][tid + o];
      red[2][tid] += red[2][tid + o];
      red[3][tid] += red[3][tid + o];
    }
    __syncthreads();
  }
  if (tid == 0) {
    st[b] = red[0][0]; st[32 + b] = red[1][0];
    st[64 + b] = red[2][0]; st[96 + b] = red[3][0];
  }
}

// build pooled [B, 7*768] from column sums + batch stats
__global__ __launch_bounds__(768) void pooled_k(
    const float* __restrict__ colsum_tok, const float* __restrict__ colsum_tsa,
    const float* __restrict__ bstat_tsa, const float* __restrict__ colsum_fsa,
    const float* __restrict__ bstat_fsa, const float* __restrict__ colsum_tgsa,
    const float* __restrict__ bstat_tgsa, const float* __restrict__ colsum_tsg,
    const float* __restrict__ gate_f, const float* __restrict__ st,
    float* __restrict__ pooled) {
  const int b = blockIdx.x, h = threadIdx.x;
  const float invS = 1.f / 512.f, invN = 1.f / (512.f * 768.f);
  const int i = b * 768 + h;
  float* pr = pooled + (size_t)b * 5376;
  pr[h] = colsum_tok[i] * invS;
  auto lnslot = [&](int slot, float cs, float bs, float bq) {
    float m = bs * invN;
    float var = bq * invN - m * m;
    pr[slot * 768 + h] = (cs * invS - m) * rsqrtf(var + 1e-8f);
  };
  lnslot(1, colsum_tsa[i], bstat_tsa[b], bstat_tsa[32 + b]);
  lnslot(2, colsum_fsa[i], bstat_fsa[b], bstat_fsa[32 + b]);
  lnslot(3, colsum_tgsa[i], bstat_tgsa[b], bstat_tgsa[32 + b]);
  const float fsg_cs = gate_f[i] * colsum_tok[i];
  lnslot(4, fsg_cs, st[64 + b], st[96 + b]);
  lnslot(5, colsum_tsg[i], st[b], st[32 + b]);
  lnslot(6, fsg_cs, st[64 + b], st[96 + b]);
}

// tmp1 += pooled-slice . W1-slice.  grid (6 colchunks, 42 kchunks), 256 thr.
__global__ __launch_bounds__(256) void fnn1_k(const float* __restrict__ pooled,
                                              const float* __restrict__ W1,
                                              float* __restrict__ tmp1) {
  __shared__ float sp[128][36];
  const int c0 = blockIdx.x << 7, k0 = blockIdx.y << 7;
  const int tid = threadIdx.x;
  for (int i = tid; i < 4096; i += 256) {
    int b = i >> 7, j = i & 127;
    sp[j][b] = pooled[(size_t)b * 5376 + k0 + j];
  }
  __syncthreads();
  const int c = c0 + (tid & 127);
  const int u = (tid >> 7) << 4;
  float acc[16];
#pragma unroll
  for (int t = 0; t < 16; ++t) acc[t] = 0.f;
#pragma unroll 4
  for (int j = 0; j < 128; ++j) {
    float w = W1[(size_t)(k0 + j) * 768 + c];
    const f32x4* row = (const f32x4*)&sp[j][u];
#pragma unroll
    for (int t4 = 0; t4 < 4; ++t4) {
      f32x4 v = row[t4];
#pragma unroll
      for (int r = 0; r < 4; ++r) acc[t4 * 4 + r] += v[r] * w;
    }
  }
#pragma unroll
  for (int t = 0; t < 16; ++t) atomicAdd(&tmp1[(u + t) * 768 + c], acc[t]);
}

// out[b,c] = sum_k (tmp1[b,k]+b1[k]) * W2[k,c] + b2[c].  One wave per output.
__global__ __launch_bounds__(256) void fnn2_k(const float* __restrict__ tmp1,
                                              const float* __restrict__ b1,
                                              const float* __restrict__ W2,
                                              const float* __restrict__ b2,
                                              float* __restrict__ out) {
  const int gw = blockIdx.x * 4 + (threadIdx.x >> 6);
  const int lane = threadIdx.x & 63;
  const int b = gw / 3, c = gw % 3;
  float a = 0.f;
#pragma unroll
  for (int i = 0; i < 12; ++i) {
    int k = lane + i * 64;
    a += (tmp1[b * 768 + k] + b1[k]) * W2[k * 3 + c];
  }
#pragma unroll
  for (int o = 32; o > 0; o >>= 1) a += __shfl_xor(a, o);
  if (lane == 0) out[b * 3 + c] = a + b2[c];
}

extern "C" void kernel_launch(void* const* d_in, const int* in_sizes, int n_in,
                              void* d_out, int out_size, void* d_ws, size_t ws_size,
                              hipStream_t stream) {
  const float* tokens = (const float*)d_in[0];
  const float* Wq = (const float*)d_in[1];
  const float* bq = (const float*)d_in[2];
  const float* Wk = (const float*)d_in[3];
  const float* bk = (const float*)d_in[4];
  const float* Wv = (const float*)d_in[5];
  const float* bv = (const float*)d_in[6];
  const float* Wts = (const float*)d_in[7];
  const float* bts = (const float*)d_in[8];
  const float* Wfs = (const float*)d_in[9];
  const float* bfs = (const float*)d_in[10];
  const float* Wtg = (const float*)d_in[11];
  const float* btg = (const float*)d_in[12];
  const float* W1 = (const float*)d_in[13];
  const float* b1 = (const float*)d_in[14];
  const float* W2 = (const float*)d_in[15];
  const float* b2 = (const float*)d_in[16];
  float* out = (float*)d_out;

  char* ws = (char*)d_ws;
  size_t off = 0;
  auto take = [&](size_t bytes) -> char* {
    char* p = ws + off;
    off += (bytes + 255) & ~(size_t)255;
    return p;
  };
  u16* tokb = (u16*)take((size_t)16384 * 768 * 2);
  u16* WqT = (u16*)take((size_t)768 * 768 * 2);  // WqT/WkT/WvT contiguous
  u16* WkT = (u16*)take((size_t)768 * 768 * 2);
  u16* WvT = (u16*)take((size_t)768 * 768 * 2);
  u16* WtgT = (u16*)take((size_t)768 * 768 * 2);
  u16* Qb = (u16*)take((size_t)16384 * 768 * 2);  // Qb/Kb/Vb contiguous
  u16* Kb = (u16*)take((size_t)16384 * 768 * 2);
  u16* Vb = (u16*)take((size_t)16384 * 768 * 2);
  u16* Qt = (u16*)take((size_t)768 * 16384 * 2);  // Qt/Kt/Vt contiguous
  u16* Kt = (u16*)take((size_t)768 * 16384 * 2);
  u16* Vt = (u16*)take((size_t)768 * 16384 * 2);
  u16* attb = (u16*)take((size_t)32 * 512 * 512 * 2);
  u16* attNb = (u16*)take((size_t)32 * 768 * 768 * 2);
  // attNt aliases Qt+Kt (both dead after the attN-score GEMM; 50.3MB >= 37.7MB)
  u16* attNt = Qt;
  float* bias3 = (float*)take(2304 * 4);
  // --- zeroed (atomic-accumulated) region: keep contiguous ---
  char* zbase = ws + off;
  float* colsum_tsa = (float*)take(24576 * 4);
  float* colsum_fsa = (float*)take(24576 * 4);
  float* colsum_tgsa = (float*)take(24576 * 4);
  float* bstat_tsa = (float*)take(64 * 4);
  float* bstat_fsa = (float*)take(64 * 4);
  float* bstat_tgsa = (float*)take(64 * 4);
  float* tmp1 = (float*)take((size_t)32 * 768 * 4);
  size_t zbytes = (size_t)((ws + off) - zbase);
  // --- fully-overwritten buffers ---
  float* colsum_tsg = (float*)take(24576 * 4);
  float* gate_t = (float*)take(16384 * 4);
  float* rowsum = (float*)take(16384 * 4);
  float* rowsumsq = (float*)take(16384 * 4);
  float* gate_f = (float*)take(24576 * 4);
  float* colsum_tok = (float*)take(24576 * 4);
  float* colsumsq_tok = (float*)take(24576 * 4);
  float* st4 = (float*)take(128 * 4);
  float* pooled = (float*)take((size_t)32 * 5376 * 4);

  hipMemsetAsync(zbase, 0, zbytes, stream);
  hipMemcpyAsync(bias3, bq, 768 * 4, hipMemcpyDeviceToDevice, stream);
  hipMemcpyAsync(bias3 + 768, bk, 768 * 4, hipMemcpyDeviceToDevice, stream);
  hipMemcpyAsync(bias3 + 1536, bv, 768 * 4, hipMemcpyDeviceToDevice, stream);

  const float scale = 1.0f / sqrtf(768.0f);
  const dim3 blk(256);

  // prep: tokens->bf16, weights->transposed bf16
  cvt_tok_k<<<6144, blk, 0, stream>>>(tokens, tokb);
  transpose_w_k<<<dim3(12, 12), blk, 0, stream>>>(Wq, WqT);
  transpose_w_k<<<dim3(12, 12), blk, 0, stream>>>(Wk, WkT);
  transpose_w_k<<<dim3(12, 12), blk, 0, stream>>>(Wv, WvT);
  transpose_w_k<<<dim3(12, 12), blk, 0, stream>>>(Wtg, WtgT);

  // fused Q|K|V projection: N=2304, C/CT split per 768-col buffer
  gemm_f_k<0><<<dim3(18, 128, 1), blk, 0, stream>>>(
      tokb, WqT, Qb, Qt, bias3, nullptr, nullptr, nullptr, 768, 768, 768, 768,
      0, 0, 12582912, 0.f);
  // TGSA (gated reduce)
  gemm_f_k<1><<<dim3(6, 128, 1), blk, 0, stream>>>(
      tokb, WtgT, nullptr, nullptr, btg, tokens, colsum_tgsa, bstat_tgsa, 768,
      768, 768, 0, 0, 0, 0, 0.f);

  // feature attention scores first (so Qt/Kt die before attNt aliases them)
  gemm_f_k<2><<<dim3(6, 6, 32), blk, 0, stream>>>(
      Qt, Kt, attNb, nullptr, nullptr, nullptr, nullptr, nullptr, 512, 16384,
      16384, 768, 512, 512, 589824, scale);
  softmax_k<768><<<24576, 256, 0, stream>>>(attNb);
  transpose_bf_k<<<dim3(12, 12, 32), blk, 0, stream>>>(attNb, attNt);

  // token attention scores: att[s,t] = Q[s,:].K[t,:] * scale
  gemm_f_k<2><<<dim3(4, 4, 32), blk, 0, stream>>>(
      Qb, Kb, attb, nullptr, nullptr, nullptr, nullptr, nullptr, 768, 768, 768,
      512, 393216, 393216, 262144, scale);
  softmax_k<512><<<16384, 256, 0, stream>>>(attb);

  // TSA = att @ V  -> reduce only
  gemm_f_k<3><<<dim3(6, 4, 32), blk, 0, stream>>>(
      attb, Vt, nullptr, nullptr, nullptr, nullptr, colsum_tsa, bstat_tsa, 512,
      512, 16384, 0, 262144, 512, 0, 0.f);
  // FSA = V @ attN -> reduce only  (B = attN^T rows)
  gemm_f_k<3><<<dim3(6, 4, 32), blk, 0, stream>>>(
      Vb, attNt, nullptr, nullptr, nullptr, nullptr, colsum_fsa, bstat_fsa, 768,
      768, 768, 0, 393216, 589824, 0, 0.f);

  // gate-branch statistics
  row_stats_k<<<4096, blk, 0, stream>>>(tokens, Wts, bts, gate_t, rowsum, rowsumsq);
  col_stats_k<<<dim3(32, 3), blk, 0, stream>>>(tokens, Wfs, bfs, gate_t, gate_f,
                                               colsum_tok, colsumsq_tok, colsum_tsg);
  batch_stats_k<<<32, blk, 0, stream>>>(gate_t, rowsum, rowsumsq, gate_f,
                                        colsum_tok, colsumsq_tok, st4);

  pooled_k<<<32, 768, 0, stream>>>(colsum_tok, colsum_tsa, bstat_tsa, colsum_fsa,
                                   bstat_fsa, colsum_tgsa, bstat_tgsa, colsum_tsg,
                                   gate_f, st4, pooled);
  fnn1_k<<<dim3(6, 42), blk, 0, stream>>>(pooled, W1, tmp1);
  fnn2_k<<<24, blk, 0, stream>>>(tmp1, b1, W2, b2, out);
}